// Round 10
// baseline (78.432 us; speedup 1.0000x reference)
//
#include <hip/hip_runtime.h>
#include <math.h>

#define E_NUM 2048
#define A_N   8
#define ROWS  (E_NUM*A_N)   // 16384

typedef __attribute__((ext_vector_type(8))) short bf16x8;
typedef __attribute__((ext_vector_type(4))) float f32x4;

__device__ __forceinline__ unsigned short f2bf(float x) {
  unsigned int u = __float_as_uint(x);
  return (unsigned short)((u + 0x7FFFu + ((u >> 16) & 1u)) >> 16);
}
#define MFMA16(a,b,c) __builtin_amdgcn_mfma_f32_16x16x32_bf16(a,b,c,0,0,0)

// ---- ws layout (float offsets) ----
#define T_WK   0         // 16*64 f32 transposed
#define T_WV1  1024      // 80*64
#define T_WV2  6144      // 64*16
#define TMB    7168      // 8*256 f32
#define B_WM1  9216      // 256x256 bf16 frag-major (32768 fl)
#define B_WM2  41984     // 128x256 (16384 fl)
#define B_WQ   58368     // 64x256 (8192 fl)
#define B_TM1  66560     // 256x64 (8192 fl)
#define B_TM2  74752     // 16x256 (2048 fl)
#define B_FC1  76800     // 64x160 (5120 fl)
#define B_WIH  81920     // 192x64 (6144 fl)
#define B_WHH  88064     // 192x64 (6144 fl)
#define O_ACT  94208     // 16384*16 f32
#define O_L1P  356352    // 512
#define O_ACC  356864    // u64
#define O_CNT  356866    // u32

// d_out: q_reflect [0,262144) ; h ; loss1 ; loss2
#define DO_H   262144
#define DO_L1  1310720
#define DO_L2  1310721

#define LD4(p) (*(const float4*)(p))

struct PrepP {
  const float* tsrc[3]; int tO[3], tK[3], tOff[3];
  const float* ssrc[8]; int sO[8], sK[8], sKs[8], sSt[8], sOff[8]; // sOff in ushort units
  const float* tm_w1; const float* tm_b1;
};

// blocks 0..23: f32 transpose ; 24..151: bf16 frag swizzle (w/ K zero-pad) ; 152..159: tmB
__global__ __launch_bounds__(256) void k_prep(PrepP p, float* __restrict__ ws,
                                              unsigned short* __restrict__ wsu) {
  int bid = blockIdx.x;
  if (bid == 0 && threadIdx.x == 0) {
    *(unsigned long long*)(ws + O_ACC) = 0ULL;
    *(unsigned int*)(ws + O_CNT) = 0u;
  }
  if (bid < 24) {
    int b = bid >> 3, sl = bid & 7;
    const float* s = p.tsrc[b];
    float* d = ws + p.tOff[b];
    int O = p.tO[b], K = p.tK[b], n = O * K;
    for (int i = sl * 256 + threadIdx.x; i < n; i += 2048) {
      int o = i / K, k = i - o * K;
      d[k * O + o] = s[i];
    }
  } else if (bid < 152) {
    int q = bid - 24, m = q >> 4, sub = q & 15;
    const float* src = p.ssrc[m];
    unsigned short* dst = wsu + p.sOff[m];
    int K = p.sK[m], Ks = p.sKs[m], stride = p.sSt[m], n = p.sO[m] * K, S = K >> 5;
    for (int f = sub * 256 + threadIdx.x; f < n; f += 16 * 256) {
      int j = f & 7, l = (f >> 3) & 63, rest = f >> 9;
      int s = rest % S, c = rest / S;
      int row = c * 16 + (l & 15), col = s * 32 + ((l >> 4) << 3) + j;
      dst[f] = (col < Ks) ? f2bf(src[row * stride + col]) : (unsigned short)0;
    }
  } else {
    int i = (bid - 152) * 256 + threadIdx.x;  // 2048
    int j = i >> 8, o = i & 255;
    ws[TMB + i] = p.tm_b1[o] + p.tm_w1[o * 72 + 64 + j];
  }
}

// fc1 + GRU (MFMA, weight-stationary): 32 rows/block, 8 waves (512 thr)
__global__ __launch_bounds__(512) void k_trunk(
    const float* __restrict__ inp, const float* __restrict__ hin,
    const unsigned short* __restrict__ fc1bf, const unsigned short* __restrict__ wihbf,
    const unsigned short* __restrict__ whhbf,
    const float* __restrict__ fc1_b, const float* __restrict__ bih, const float* __restrict__ bhh,
    float* __restrict__ hout)
{
  __shared__ __align__(16) unsigned short in_b[32 * 168];
  __shared__ __align__(16) unsigned short x_b[32 * 72];
  __shared__ __align__(16) unsigned short h_b[32 * 72];
  int tid = threadIdx.x, w = tid >> 6, lane = tid & 63;
  int lo = lane & 15, hi = lane >> 4;
  int row0 = blockIdx.x * 32;
  int c = w & 3, rt = w >> 2;

  for (int i = tid; i < 32 * 152; i += 512) {
    int r = i / 152, cc = i - r * 152;
    in_b[r * 168 + cc] = f2bf(inp[(size_t)(row0 + r) * 152 + cc]);
  }
  if (tid < 256) { int r = tid >> 3, cc = tid & 7; in_b[r * 168 + 152 + cc] = 0; }
  for (int i = tid; i < 32 * 64; i += 512) {
    int r = i >> 6, cc = i & 63;
    h_b[r * 72 + cc] = f2bf(hin[(size_t)(row0 + r) * 64 + cc]);
  }
  __syncthreads();

  bf16x8 wf1[5];
#pragma unroll
  for (int s = 0; s < 5; s++)
    wf1[s] = *(const bf16x8*)(fc1bf + (size_t)((c * 5 + s) * 64 + lane) * 8);
  f32x4 acc = {0, 0, 0, 0};
#pragma unroll
  for (int s = 0; s < 5; s++) {
    bf16x8 af = *(const bf16x8*)(in_b + (rt * 16 + lo) * 168 + s * 32 + hi * 8);
    acc = MFMA16(af, wf1[s], acc);
  }
  float fb = fc1_b[16 * c + lo];
#pragma unroll
  for (int r = 0; r < 4; r++)
    x_b[(rt * 16 + hi * 4 + r) * 72 + 16 * c + lo] = f2bf(fmaxf(acc[r] + fb, 0.f));
  __syncthreads();

  bf16x8 wfi[3][2], wfh[3][2];
#pragma unroll
  for (int t = 0; t < 3; t++)
#pragma unroll
    for (int s = 0; s < 2; s++) {
      int chunk = c + 4 * t;
      wfi[t][s] = *(const bf16x8*)(wihbf + (size_t)((chunk * 2 + s) * 64 + lane) * 8);
      wfh[t][s] = *(const bf16x8*)(whhbf + (size_t)((chunk * 2 + s) * 64 + lane) * 8);
    }
  f32x4 ai[3], ah[3];
#pragma unroll
  for (int t = 0; t < 3; t++) { ai[t] = {0,0,0,0}; ah[t] = {0,0,0,0}; }
#pragma unroll
  for (int s = 0; s < 2; s++) {
    bf16x8 ax  = *(const bf16x8*)(x_b + (rt * 16 + lo) * 72 + s * 32 + hi * 8);
    bf16x8 ahv = *(const bf16x8*)(h_b + (rt * 16 + lo) * 72 + s * 32 + hi * 8);
#pragma unroll
    for (int t = 0; t < 3; t++) {
      ai[t] = MFMA16(ax,  wfi[t][s], ai[t]);
      ah[t] = MFMA16(ahv, wfh[t][s], ah[t]);
    }
  }
  int col = 16 * c + lo;
  float b_ir = bih[col],       b_hr = bhh[col];
  float b_iz = bih[64 + col],  b_hz = bhh[64 + col];
  float b_in = bih[128 + col], b_hn = bhh[128 + col];
#pragma unroll
  for (int r = 0; r < 4; r++) {
    size_t grow = (size_t)(row0 + rt * 16 + hi * 4 + r);
    float rg = 1.f / (1.f + expf(-(ai[0][r] + b_ir + ah[0][r] + b_hr)));
    float zg = 1.f / (1.f + expf(-(ai[1][r] + b_iz + ah[1][r] + b_hz)));
    float ng = tanhf(fmaf(rg, ah[2][r] + b_hn, ai[2][r] + b_in));
    float h0 = hin[grow * 64 + col];
    hout[grow * 64 + col] = (1.f - zg) * ng + zg * h0;
  }
}

// teammate MLP + CE (MFMA, weight-stationary): 32 rows/block, 8 waves
__global__ __launch_bounds__(512) void k_tm(
    const float* __restrict__ h,
    const unsigned short* __restrict__ w1b, const unsigned short* __restrict__ w2b,
    const float* __restrict__ tmB, const float* __restrict__ b2,
    const int* __restrict__ u,
    float* __restrict__ act, float* __restrict__ l1p)
{
  __shared__ __align__(16) unsigned short in_s[32 * 72];
  __shared__ __align__(16) unsigned short hid_s[32 * 264];
  __shared__ float red[512];
  int tid = threadIdx.x, w = tid >> 6, lane = tid & 63;
  int lo = lane & 15, hi = lane >> 4;
  int row0 = blockIdx.x * 32;
  for (int i = tid; i < 2048; i += 512) {
    int r = i >> 6, c = i & 63;
    in_s[r * 72 + c] = f2bf(h[(size_t)(row0 + r) * 64 + c]);
  }
  bf16x8 wf1[2][2];
#pragma unroll
  for (int cc = 0; cc < 2; cc++)
#pragma unroll
    for (int s = 0; s < 2; s++)
      wf1[cc][s] = *(const bf16x8*)(w1b + (size_t)(((2 * w + cc) * 2 + s) * 64 + lane) * 8);
  __syncthreads();
  f32x4 acc[2][2];
#pragma unroll
  for (int rt = 0; rt < 2; rt++) { acc[rt][0] = {0,0,0,0}; acc[rt][1] = {0,0,0,0}; }
#pragma unroll
  for (int s = 0; s < 2; s++)
#pragma unroll
    for (int rt = 0; rt < 2; rt++) {
      bf16x8 af = *(const bf16x8*)(in_s + (rt * 16 + lo) * 72 + s * 32 + hi * 8);
      acc[rt][0] = MFMA16(af, wf1[0][s], acc[rt][0]);
      acc[rt][1] = MFMA16(af, wf1[1][s], acc[rt][1]);
    }
#pragma unroll
  for (int rt = 0; rt < 2; rt++)
#pragma unroll
    for (int r = 0; r < 4; r++) {
      int rowl = rt * 16 + hi * 4 + r, j = (hi * 4 + r) & 7;
      float v0 = acc[rt][0][r] + tmB[j * 256 + 32 * w + lo];
      float v1 = acc[rt][1][r] + tmB[j * 256 + 32 * w + 16 + lo];
      hid_s[rowl * 264 + 32 * w + lo]      = f2bf(fmaxf(v0, 0.f));
      hid_s[rowl * 264 + 32 * w + 16 + lo] = f2bf(fmaxf(v1, 0.f));
    }
  __syncthreads();
  float ces = 0.f;
  if (w < 2) {
    bf16x8 wf2[8];
#pragma unroll
    for (int s = 0; s < 8; s++)
      wf2[s] = *(const bf16x8*)(w2b + (size_t)(s * 64 + lane) * 8);
    f32x4 a2 = {0, 0, 0, 0};
#pragma unroll
    for (int s = 0; s < 8; s++) {
      bf16x8 af = *(const bf16x8*)(hid_s + (w * 16 + lo) * 264 + s * 32 + hi * 8);
      a2 = MFMA16(af, wf2[s], a2);
    }
    float b2c = b2[lo];
#pragma unroll
    for (int r = 0; r < 4; r++) {
      int rowl = w * 16 + hi * 4 + r;
      float v = a2[r] + b2c;
      act[(size_t)(row0 + rowl) * 16 + lo] = v;
      float m = v;
      m = fmaxf(m, __shfl_xor(m, 1));
      m = fmaxf(m, __shfl_xor(m, 2));
      m = fmaxf(m, __shfl_xor(m, 4));
      m = fmaxf(m, __shfl_xor(m, 8));
      float se = expf(v - m);
      se += __shfl_xor(se, 1);
      se += __shfl_xor(se, 2);
      se += __shfl_xor(se, 4);
      se += __shfl_xor(se, 8);
      int lbl = u[row0 + rowl];
      float vl = __shfl(v, (lane & 48) + lbl);
      if (lo == 0) ces += -(vl - m - logf(se));
    }
  }
  red[tid] = ces;
  __syncthreads();
  for (int st = 256; st > 0; st >>= 1) {
    if (tid < st) red[tid] += red[tid + st];
    __syncthreads();
  }
  if (tid == 0) l1p[blockIdx.x] = red[0];
}

// wm + MSE + query + key + value + attention: 16 rows/block, 8 waves, 1024 blocks
__global__ __launch_bounds__(512) void k_wmkva(
    const float* __restrict__ obs, const float* __restrict__ act,
    const float* __restrict__ h,
    const unsigned short* __restrict__ w1b, const unsigned short* __restrict__ w2b,
    const unsigned short* __restrict__ wqb,
    const float* __restrict__ b1, const float* __restrict__ b2, const float* __restrict__ bq,
    const float* __restrict__ obsn, const float* __restrict__ ws,
    const float* __restrict__ bk, const float* __restrict__ bv1, const float* __restrict__ bv2,
    const float* __restrict__ l1p, unsigned long long* __restrict__ accp,
    unsigned int* __restrict__ cntp, float* __restrict__ qout)
{
  __shared__ __align__(16) unsigned short in_s[16 * 264];   // [obs | masked act] -> hid overlay
  __shared__ __align__(16) unsigned short q_in[16 * 264];   // [obs | onh]
  __shared__ __align__(16) unsigned short act_bs[256];
  __shared__ __align__(16) float kin_s[16 * 80];            // [h | act] f32
  __shared__ __align__(16) float hid_k[16 * 64];
  __shared__ __align__(16) float key_s[16 * 68];
  __shared__ __align__(16) float qry_s[16 * 68];
  __shared__ float val_s[256];                               // 2 episodes x 8 x 16
  __shared__ float red[512];
  int tid = threadIdx.x, w = tid >> 6, lane = tid & 63;
  int lo = lane & 15, hi = lane >> 4;
  int row0 = blockIdx.x * 16, e0 = row0 >> 3;

  if (blockIdx.x == 0) {   // finalize loss1 (l1p fully written by k_tm)
    red[tid] = l1p[tid];
    __syncthreads();
    for (int s = 256; s > 0; s >>= 1) {
      if (tid < s) red[tid] += red[tid + s];
      __syncthreads();
    }
    if (tid == 0) qout[DO_L1] = red[0] * 7.f / 131072.f;
    __syncthreads();
  }

  if (tid < 256) act_bs[tid] = f2bf(act[(size_t)e0 * 128 + tid]);
  for (int i = tid; i < 2048; i += 512) {
    int r = i >> 7, c = i & 127;
    unsigned short v = f2bf(obs[(size_t)(row0 + r) * 128 + c]);
    in_s[r * 264 + c] = v;
    q_in[r * 264 + c] = v;
  }
  for (int i = tid; i < 1024; i += 512) {
    int r = i >> 6, c = i & 63;
    kin_s[r * 80 + c] = h[(size_t)(row0 + r) * 64 + c];
  }
  if (tid < 256) {
    int r = tid >> 4, c = tid & 15;
    kin_s[r * 80 + 64 + c] = act[(size_t)(row0 + r) * 16 + c];
  }
  bf16x8 wf1[2][8], wf2[8];
#pragma unroll
  for (int cc = 0; cc < 2; cc++)
#pragma unroll
    for (int s = 0; s < 8; s++)
      wf1[cc][s] = *(const bf16x8*)(w1b + (size_t)(((2 * w + cc) * 8 + s) * 64 + lane) * 8);
#pragma unroll
  for (int s = 0; s < 8; s++)
    wf2[s] = *(const bf16x8*)(w2b + (size_t)((w * 8 + s) * 64 + lane) * 8);
  __syncthreads();
  for (int i = tid; i < 2048; i += 512) {
    int r = i >> 7, c = i & 127;
    in_s[r * 264 + 128 + c] = ((c >> 4) == (r & 7)) ? (unsigned short)0 : act_bs[(r >> 3) * 128 + c];
  }
  __syncthreads();
  // ---- wm layer1: wave w -> cols [32w, 32w+32), rows 0..15 ----
  f32x4 acc[2];
  acc[0] = {0, 0, 0, 0}; acc[1] = {0, 0, 0, 0};
#pragma unroll
  for (int s = 0; s < 8; s++) {
    bf16x8 af = *(const bf16x8*)(in_s + lo * 264 + s * 32 + hi * 8);
    acc[0] = MFMA16(af, wf1[0][s], acc[0]);
    acc[1] = MFMA16(af, wf1[1][s], acc[1]);
  }
  float b1a = b1[32 * w + lo], b1b = b1[32 * w + 16 + lo];
  __syncthreads();
#pragma unroll
  for (int r = 0; r < 4; r++) {
    int rowl = hi * 4 + r;
    in_s[rowl * 264 + 32 * w + lo]      = f2bf(fmaxf(acc[0][r] + b1a, 0.f));
    in_s[rowl * 264 + 32 * w + 16 + lo] = f2bf(fmaxf(acc[1][r] + b1b, 0.f));
  }
  __syncthreads();
  // ---- wm layer2: wave w -> cols [16w, 16w+16) ; onh -> q_in + MSE ----
  f32x4 acc2 = {0, 0, 0, 0};
#pragma unroll
  for (int s = 0; s < 8; s++) {
    bf16x8 af = *(const bf16x8*)(in_s + lo * 264 + s * 32 + hi * 8);
    acc2 = MFMA16(af, wf2[s], acc2);
  }
  float ms = 0.f;
  {
    int col = 16 * w + lo;
    float b2c = b2[col];
#pragma unroll
    for (int r = 0; r < 4; r++) {
      int rowl = hi * 4 + r;
      float v = acc2[r] + b2c;
      q_in[rowl * 264 + 128 + col] = f2bf(v);
      float d = v - obsn[(size_t)(row0 + rowl) * 128 + col];
      ms = fmaf(d, d, ms);
    }
  }
  __syncthreads();
  // ---- waves 0-3: query MFMA -> qry_s ; waves 4-7: value l1 + key -> hid_k/key_s ----
  if (w < 4) {
    bf16x8 wf3[8];
#pragma unroll
    for (int s = 0; s < 8; s++)
      wf3[s] = *(const bf16x8*)(wqb + (size_t)((w * 8 + s) * 64 + lane) * 8);
    f32x4 aq = {0, 0, 0, 0};
#pragma unroll
    for (int s = 0; s < 8; s++) {
      bf16x8 af = *(const bf16x8*)(q_in + lo * 264 + s * 32 + hi * 8);
      aq = MFMA16(af, wf3[s], aq);
    }
    float bqc = bq[16 * w + lo];
#pragma unroll
    for (int r = 0; r < 4; r++)
      qry_s[(hi * 4 + r) * 68 + 16 * w + lo] = aq[r] + bqc;
  } else {
    const float* w1T = ws + T_WV1;
    const float* wkT = ws + T_WK;
    int r0 = (w - 4) * 4;
    float a1[4], ka[4];
#pragma unroll
    for (int r = 0; r < 4; r++) { a1[r] = bv1[lane]; ka[r] = bk[lane]; }
    for (int k = 0; k < 80; k += 4) {
      float b[4];
#pragma unroll
      for (int j = 0; j < 4; j++) b[j] = w1T[(k + j) * 64 + lane];
#pragma unroll
      for (int r = 0; r < 4; r++) {
        float4 a = LD4(kin_s + (r0 + r) * 80 + k);
        a1[r] = fmaf(a.x, b[0], fmaf(a.y, b[1], fmaf(a.z, b[2], fmaf(a.w, b[3], a1[r]))));
      }
    }
    for (int k = 0; k < 16; k += 4) {
      float b[4];
#pragma unroll
      for (int j = 0; j < 4; j++) b[j] = wkT[(k + j) * 64 + lane];
#pragma unroll
      for (int r = 0; r < 4; r++) {
        float4 a = LD4(kin_s + (r0 + r) * 80 + 64 + k);
        ka[r] = fmaf(a.x, b[0], fmaf(a.y, b[1], fmaf(a.z, b[2], fmaf(a.w, b[3], ka[r]))));
      }
    }
#pragma unroll
    for (int r = 0; r < 4; r++) {
      hid_k[(r0 + r) * 64 + lane] = fmaxf(a1[r], 0.f);
      key_s[(r0 + r) * 68 + lane] = ka[r];
    }
  }
  __syncthreads();
  // ---- value l2 (waves 0-3, 4 rows each) ----
  if (w < 4) {
    const float* w2T = ws + T_WV2;
    int col = lane & 15, kq = lane >> 4;
    float a2[4] = {0, 0, 0, 0};
    for (int kk = 0; kk < 16; kk += 4) {
      int k = kq * 16 + kk;
      float b[4];
#pragma unroll
      for (int j = 0; j < 4; j++) b[j] = w2T[(k + j) * 16 + col];
#pragma unroll
      for (int r = 0; r < 4; r++) {
        float4 a = LD4(hid_k + (w * 4 + r) * 64 + k);
        a2[r] = fmaf(a.x, b[0], fmaf(a.y, b[1], fmaf(a.z, b[2], fmaf(a.w, b[3], a2[r]))));
      }
    }
#pragma unroll
    for (int r = 0; r < 4; r++) {
      a2[r] += __shfl_xor(a2[r], 16);
      a2[r] += __shfl_xor(a2[r], 32);
    }
    if (lane < 16)
#pragma unroll
      for (int r = 0; r < 4; r++) val_s[(w * 4 + r) * 16 + col] = a2[r] + bv2[col];
  }
  __syncthreads();
  // ---- attention: wave w -> episode ep=w&1, rows (w>>1)*2 .. +1 ----
  {
    int ep = w & 1, pr = w >> 1;
    int j = lane >> 3, p = lane & 7;
#pragma unroll
    for (int q2 = 0; q2 < 2; q2++) {
      int rr = pr * 2 + q2;          // agent index within episode
      int bl = ep * 8 + rr;          // local row
      float s = 0.f;
#pragma unroll
      for (int t = 0; t < 8; t++) {
        int d = p * 8 + t;
        s = fmaf(qry_s[bl * 68 + d], key_s[(ep * 8 + j) * 68 + d], s);
      }
      s += __shfl_xor(s, 1);
      s += __shfl_xor(s, 2);
      s += __shfl_xor(s, 4);
      float score = (j == rr) ? -1e9f : s * 0.125f;
      float sc[8];
      float m = -1e30f;
#pragma unroll
      for (int jj = 0; jj < 8; jj++) {
        sc[jj] = __shfl(score, jj * 8);
        m = fmaxf(m, sc[jj]);
      }
      float ssum = 0.f;
#pragma unroll
      for (int jj = 0; jj < 8; jj++) { sc[jj] = expf(sc[jj] - m); ssum += sc[jj]; }
      float inv = 1.f / ssum;
      int c = lane & 15, g = lane >> 4;
      const float* vb = val_s + ep * 128;
      float outv = sc[g] * inv * vb[g * 16 + c] + sc[g + 4] * inv * vb[(g + 4) * 16 + c];
      outv += __shfl_xor(outv, 16);
      outv += __shfl_xor(outv, 32);
      if (lane < 16) qout[(size_t)(row0 + bl) * 16 + lane] = outv;
    }
  }
  // ---- MSE block-reduce + fixed-point atomic + last-block finalize ----
  __syncthreads();
  red[tid] = ms;
  __syncthreads();
  for (int st = 256; st > 0; st >>= 1) {
    if (tid < st) red[tid] += red[tid + st];
    __syncthreads();
  }
  if (tid == 0) {
    unsigned long long fx = (unsigned long long)(long long)llrintf(red[0] * 1048576.f);
    atomicAdd(accp, fx);
    __threadfence();
    unsigned int prev = atomicAdd(cntp, 1u);
    if (prev == gridDim.x - 1) {
      unsigned long long tot = atomicAdd(accp, 0ULL);
      qout[DO_L2] = (float)((double)tot / 1048576.0 / 2097152.0);
    }
  }
}

extern "C" void kernel_launch(void* const* d_in, const int* in_sizes, int n_in,
                              void* d_out, int out_size, void* d_ws, size_t ws_size,
                              hipStream_t stream) {
  const float* inputs   = (const float*)d_in[0];
  const float* hidden   = (const float*)d_in[1];
  const float* obs      = (const float*)d_in[2];
  const float* obs_next = (const float*)d_in[3];
  const int*   u        = (const int*)d_in[4];
  const float* fc1_w = (const float*)d_in[5];   const float* fc1_b = (const float*)d_in[6];
  const float* wih   = (const float*)d_in[7];   const float* bih   = (const float*)d_in[8];
  const float* whh   = (const float*)d_in[9];   const float* bhh   = (const float*)d_in[10];
  const float* tm_w1 = (const float*)d_in[11];  const float* tm_b1 = (const float*)d_in[12];
  const float* tm_w2 = (const float*)d_in[13];  const float* tm_b2 = (const float*)d_in[14];
  const float* wm_w1 = (const float*)d_in[15];  const float* wm_b1 = (const float*)d_in[16];
  const float* wm_w2 = (const float*)d_in[17];  const float* wm_b2 = (const float*)d_in[18];
  const float* wq_w  = (const float*)d_in[19];  const float* wq_b  = (const float*)d_in[20];
  const float* wk_w  = (const float*)d_in[21];  const float* wk_b  = (const float*)d_in[22];
  const float* wv1_w = (const float*)d_in[23];  const float* wv1_b = (const float*)d_in[24];
  const float* wv2_w = (const float*)d_in[25];  const float* wv2_b = (const float*)d_in[26];

  float* ws   = (float*)d_ws;
  unsigned short* wsu = (unsigned short*)d_ws;
  float* out  = (float*)d_out;
  float* hbuf = out + DO_H;

  PrepP p;
  const float* tsr[3] = {wk_w, wv1_w, wv2_w};
  int tO[3]  = {64, 64, 16};
  int tK[3]  = {16, 80, 64};
  int tOf[3] = {T_WK, T_WV1, T_WV2};
  for (int i = 0; i < 3; i++) { p.tsrc[i] = tsr[i]; p.tO[i] = tO[i]; p.tK[i] = tK[i]; p.tOff[i] = tOf[i]; }
  const float* ssr[8] = {wm_w1, wm_w2, wq_w, tm_w1, tm_w2, fc1_w, wih, whh};
  int sO[8]  = {256, 128, 64, 256, 16, 64, 192, 192};
  int sK[8]  = {256, 256, 256, 64, 256, 160, 64, 64};
  int sKs[8] = {256, 256, 256, 64, 256, 152, 64, 64};
  int sSt[8] = {256, 256, 256, 72, 256, 152, 64, 64};
  int sOf[8] = {B_WM1*2, B_WM2*2, B_WQ*2, B_TM1*2, B_TM2*2, B_FC1*2, B_WIH*2, B_WHH*2};
  for (int i = 0; i < 8; i++) {
    p.ssrc[i] = ssr[i]; p.sO[i] = sO[i]; p.sK[i] = sK[i];
    p.sKs[i] = sKs[i]; p.sSt[i] = sSt[i]; p.sOff[i] = sOf[i];
  }
  p.tm_w1 = tm_w1; p.tm_b1 = tm_b1;

  k_prep<<<160, 256, 0, stream>>>(p, ws, wsu);
  k_trunk<<<ROWS / 32, 512, 0, stream>>>(inputs, hidden,
      wsu + B_FC1*2, wsu + B_WIH*2, wsu + B_WHH*2, fc1_b, bih, bhh, hbuf);
  k_tm<<<ROWS / 32, 512, 0, stream>>>(hbuf, wsu + B_TM1*2, wsu + B_TM2*2,
      ws + TMB, tm_b2, u, ws + O_ACT, ws + O_L1P);
  k_wmkva<<<ROWS / 16, 512, 0, stream>>>(obs, ws + O_ACT, hbuf,
      wsu + B_WM1*2, wsu + B_WM2*2, wsu + B_WQ*2, wm_b1, wm_b2, wq_b, obs_next,
      ws, wk_b, wv1_b, wv2_b, ws + O_L1P,
      (unsigned long long*)(ws + O_ACC), (unsigned int*)(ws + O_CNT), out);
}

// Round 11
// 56.665 us; speedup vs baseline: 1.3841x; 1.3841x over previous
//
#include <hip/hip_runtime.h>
#include <math.h>

#define E_NUM 2048
#define A_N   8
#define ROWS  (E_NUM*A_N)   // 16384

typedef __attribute__((ext_vector_type(8))) short bf16x8;
typedef __attribute__((ext_vector_type(4))) float f32x4;

__device__ __forceinline__ unsigned short f2bf(float x) {
  unsigned int u = __float_as_uint(x);
  return (unsigned short)((u + 0x7FFFu + ((u >> 16) & 1u)) >> 16);
}
__device__ __forceinline__ ushort4 f2bf4(float4 v) {
  return make_ushort4(f2bf(v.x), f2bf(v.y), f2bf(v.z), f2bf(v.w));
}
#define MFMA16(a,b,c) __builtin_amdgcn_mfma_f32_16x16x32_bf16(a,b,c,0,0,0)

// ---- ws layout (float offsets) ----
#define T_WK   0         // 16*64 f32 transposed
#define T_WV1  1024      // 80*64
#define T_WV2  6144      // 64*16
#define TMB    7168      // 8*256 f32
#define B_WM1  9216      // 256x256 bf16 frag-major (32768 fl)
#define B_WM2  41984     // 128x256 (16384 fl)
#define B_WQ   58368     // 64x256 (8192 fl)
#define B_TM1  66560     // 256x64 (8192 fl)
#define B_TM2  74752     // 16x256 (2048 fl)
#define B_FC1  76800     // 64x160 (5120 fl)
#define B_WIH  81920     // 192x64 (6144 fl)
#define B_WHH  88064     // 192x64 (6144 fl)
#define O_ACT  94208     // 16384*16 f32
#define O_QRY  356352    // 16384*64 f32
#define O_L1P  1404928   // 512
#define O_L2P  1405440   // 512

// d_out: q_reflect [0,262144) ; h ; loss1 ; loss2
#define DO_H   262144
#define DO_L1  1310720
#define DO_L2  1310721

#define LD4(p) (*(const float4*)(p))

struct PrepP {
  const float* tsrc[3]; int tO[3], tK[3], tOff[3];
  const float* ssrc[8]; int sO[8], sK[8], sKs[8], sSt[8], sOff[8]; // sOff in ushort units
  const float* tm_w1; const float* tm_b1;
};

// blocks 0..23: f32 transpose ; 24..151: bf16 frag swizzle (w/ K zero-pad) ; 152..159: tmB
__global__ __launch_bounds__(256) void k_prep(PrepP p, float* __restrict__ ws,
                                              unsigned short* __restrict__ wsu) {
  int bid = blockIdx.x;
  if (bid < 24) {
    int b = bid >> 3, sl = bid & 7;
    const float* s = p.tsrc[b];
    float* d = ws + p.tOff[b];
    int O = p.tO[b], K = p.tK[b], n = O * K;
    for (int i = sl * 256 + threadIdx.x; i < n; i += 2048) {
      int o = i / K, k = i - o * K;
      d[k * O + o] = s[i];
    }
  } else if (bid < 152) {
    int q = bid - 24, m = q >> 4, sub = q & 15;
    const float* src = p.ssrc[m];
    unsigned short* dst = wsu + p.sOff[m];
    int K = p.sK[m], Ks = p.sKs[m], stride = p.sSt[m], n = p.sO[m] * K, S = K >> 5;
    for (int f = sub * 256 + threadIdx.x; f < n; f += 16 * 256) {
      int j = f & 7, l = (f >> 3) & 63, rest = f >> 9;
      int s = rest % S, c = rest / S;
      int row = c * 16 + (l & 15), col = s * 32 + ((l >> 4) << 3) + j;
      dst[f] = (col < Ks) ? f2bf(src[row * stride + col]) : (unsigned short)0;
    }
  } else {
    int i = (bid - 152) * 256 + threadIdx.x;  // 2048
    int j = i >> 8, o = i & 255;
    ws[TMB + i] = p.tm_b1[o] + p.tm_w1[o * 72 + 64 + j];
  }
}

// fc1 + GRU (MFMA, weight-stationary): 32 rows/block, 8 waves (512 thr)
__global__ __launch_bounds__(512) void k_trunk(
    const float* __restrict__ inp, const float* __restrict__ hin,
    const unsigned short* __restrict__ fc1bf, const unsigned short* __restrict__ wihbf,
    const unsigned short* __restrict__ whhbf,
    const float* __restrict__ fc1_b, const float* __restrict__ bih, const float* __restrict__ bhh,
    float* __restrict__ hout)
{
  __shared__ __align__(16) unsigned short in_b[32 * 168];
  __shared__ __align__(16) unsigned short x_b[32 * 72];
  __shared__ __align__(16) unsigned short h_b[32 * 72];
  int tid = threadIdx.x, w = tid >> 6, lane = tid & 63;
  int lo = lane & 15, hi = lane >> 4;
  int row0 = blockIdx.x * 32;
  int c = w & 3, rt = w >> 2;

  // staging: float4 loads + ushort4 LDS writes
  for (int i = tid; i < 1216; i += 512) {              // 32*152/4
    int e = i << 2;
    int r = e / 152, cc = e - r * 152;
    float4 v = LD4(inp + (size_t)(row0 + r) * 152 + cc);
    *(ushort4*)(in_b + r * 168 + cc) = f2bf4(v);
  }
  if (tid < 256) { int r = tid >> 3, cc = tid & 7; in_b[r * 168 + 152 + cc] = 0; }
  {
    int r = tid >> 4, cc = (tid & 15) << 2;            // 512 float4s, one per thread
    float4 v = LD4(hin + (size_t)(row0 + r) * 64 + cc);
    *(ushort4*)(h_b + r * 72 + cc) = f2bf4(v);
  }
  __syncthreads();

  bf16x8 wf1[5];
#pragma unroll
  for (int s = 0; s < 5; s++)
    wf1[s] = *(const bf16x8*)(fc1bf + (size_t)((c * 5 + s) * 64 + lane) * 8);
  f32x4 acc = {0, 0, 0, 0};
#pragma unroll
  for (int s = 0; s < 5; s++) {
    bf16x8 af = *(const bf16x8*)(in_b + (rt * 16 + lo) * 168 + s * 32 + hi * 8);
    acc = MFMA16(af, wf1[s], acc);
  }
  float fb = fc1_b[16 * c + lo];
#pragma unroll
  for (int r = 0; r < 4; r++)
    x_b[(rt * 16 + hi * 4 + r) * 72 + 16 * c + lo] = f2bf(fmaxf(acc[r] + fb, 0.f));
  __syncthreads();

  bf16x8 wfi[3][2], wfh[3][2];
#pragma unroll
  for (int t = 0; t < 3; t++)
#pragma unroll
    for (int s = 0; s < 2; s++) {
      int chunk = c + 4 * t;
      wfi[t][s] = *(const bf16x8*)(wihbf + (size_t)((chunk * 2 + s) * 64 + lane) * 8);
      wfh[t][s] = *(const bf16x8*)(whhbf + (size_t)((chunk * 2 + s) * 64 + lane) * 8);
    }
  f32x4 ai[3], ah[3];
#pragma unroll
  for (int t = 0; t < 3; t++) { ai[t] = {0,0,0,0}; ah[t] = {0,0,0,0}; }
#pragma unroll
  for (int s = 0; s < 2; s++) {
    bf16x8 ax  = *(const bf16x8*)(x_b + (rt * 16 + lo) * 72 + s * 32 + hi * 8);
    bf16x8 ahv = *(const bf16x8*)(h_b + (rt * 16 + lo) * 72 + s * 32 + hi * 8);
#pragma unroll
    for (int t = 0; t < 3; t++) {
      ai[t] = MFMA16(ax,  wfi[t][s], ai[t]);
      ah[t] = MFMA16(ahv, wfh[t][s], ah[t]);
    }
  }
  int col = 16 * c + lo;
  float b_ir = bih[col],       b_hr = bhh[col];
  float b_iz = bih[64 + col],  b_hz = bhh[64 + col];
  float b_in = bih[128 + col], b_hn = bhh[128 + col];
#pragma unroll
  for (int r = 0; r < 4; r++) {
    size_t grow = (size_t)(row0 + rt * 16 + hi * 4 + r);
    float rg = 1.f / (1.f + expf(-(ai[0][r] + b_ir + ah[0][r] + b_hr)));
    float zg = 1.f / (1.f + expf(-(ai[1][r] + b_iz + ah[1][r] + b_hz)));
    float ng = tanhf(fmaf(rg, ah[2][r] + b_hn, ai[2][r] + b_in));
    float h0 = hin[grow * 64 + col];
    hout[grow * 64 + col] = (1.f - zg) * ng + zg * h0;
  }
}

// teammate MLP + CE (MFMA, weight-stationary): 32 rows/block, 8 waves
__global__ __launch_bounds__(512) void k_tm(
    const float* __restrict__ h,
    const unsigned short* __restrict__ w1b, const unsigned short* __restrict__ w2b,
    const float* __restrict__ tmB, const float* __restrict__ b2,
    const int* __restrict__ u,
    float* __restrict__ act, float* __restrict__ l1p)
{
  __shared__ __align__(16) unsigned short in_s[32 * 72];
  __shared__ __align__(16) unsigned short hid_s[32 * 264];
  __shared__ float red[512];
  int tid = threadIdx.x, w = tid >> 6, lane = tid & 63;
  int lo = lane & 15, hi = lane >> 4;
  int row0 = blockIdx.x * 32;
  {
    int r = tid >> 4, cc = (tid & 15) << 2;            // 512 float4s
    float4 v = LD4(h + (size_t)(row0 + r) * 64 + cc);
    *(ushort4*)(in_s + r * 72 + cc) = f2bf4(v);
  }
  bf16x8 wf1[2][2];
#pragma unroll
  for (int cc = 0; cc < 2; cc++)
#pragma unroll
    for (int s = 0; s < 2; s++)
      wf1[cc][s] = *(const bf16x8*)(w1b + (size_t)(((2 * w + cc) * 2 + s) * 64 + lane) * 8);
  __syncthreads();
  f32x4 acc[2][2];
#pragma unroll
  for (int rt = 0; rt < 2; rt++) { acc[rt][0] = {0,0,0,0}; acc[rt][1] = {0,0,0,0}; }
#pragma unroll
  for (int s = 0; s < 2; s++)
#pragma unroll
    for (int rt = 0; rt < 2; rt++) {
      bf16x8 af = *(const bf16x8*)(in_s + (rt * 16 + lo) * 72 + s * 32 + hi * 8);
      acc[rt][0] = MFMA16(af, wf1[0][s], acc[rt][0]);
      acc[rt][1] = MFMA16(af, wf1[1][s], acc[rt][1]);
    }
#pragma unroll
  for (int rt = 0; rt < 2; rt++)
#pragma unroll
    for (int r = 0; r < 4; r++) {
      int rowl = rt * 16 + hi * 4 + r, j = (hi * 4 + r) & 7;
      float v0 = acc[rt][0][r] + tmB[j * 256 + 32 * w + lo];
      float v1 = acc[rt][1][r] + tmB[j * 256 + 32 * w + 16 + lo];
      hid_s[rowl * 264 + 32 * w + lo]      = f2bf(fmaxf(v0, 0.f));
      hid_s[rowl * 264 + 32 * w + 16 + lo] = f2bf(fmaxf(v1, 0.f));
    }
  __syncthreads();
  float ces = 0.f;
  if (w < 2) {
    bf16x8 wf2[8];
#pragma unroll
    for (int s = 0; s < 8; s++)
      wf2[s] = *(const bf16x8*)(w2b + (size_t)(s * 64 + lane) * 8);
    f32x4 a2 = {0, 0, 0, 0};
#pragma unroll
    for (int s = 0; s < 8; s++) {
      bf16x8 af = *(const bf16x8*)(hid_s + (w * 16 + lo) * 264 + s * 32 + hi * 8);
      a2 = MFMA16(af, wf2[s], a2);
    }
    float b2c = b2[lo];
#pragma unroll
    for (int r = 0; r < 4; r++) {
      int rowl = w * 16 + hi * 4 + r;
      float v = a2[r] + b2c;
      act[(size_t)(row0 + rowl) * 16 + lo] = v;
      float m = v;
      m = fmaxf(m, __shfl_xor(m, 1));
      m = fmaxf(m, __shfl_xor(m, 2));
      m = fmaxf(m, __shfl_xor(m, 4));
      m = fmaxf(m, __shfl_xor(m, 8));
      float se = expf(v - m);
      se += __shfl_xor(se, 1);
      se += __shfl_xor(se, 2);
      se += __shfl_xor(se, 4);
      se += __shfl_xor(se, 8);
      int lbl = u[row0 + rowl];
      float vl = __shfl(v, (lane & 48) + lbl);
      if (lo == 0) ces += -(vl - m - logf(se));
    }
  }
  red[tid] = ces;
  __syncthreads();
  for (int st = 256; st > 0; st >>= 1) {
    if (tid < st) red[tid] += red[tid + st];
    __syncthreads();
  }
  if (tid == 0) l1p[blockIdx.x] = red[0];
}

// world model + MSE + query: 32 rows/block, 8 waves
__global__ __launch_bounds__(512) void k_wm(
    const float* __restrict__ obs, const float* __restrict__ act,
    const unsigned short* __restrict__ w1b, const unsigned short* __restrict__ w2b,
    const unsigned short* __restrict__ wqb,
    const float* __restrict__ b1, const float* __restrict__ b2, const float* __restrict__ bq,
    const float* __restrict__ obsn,
    float* __restrict__ qry, float* __restrict__ l2p)
{
  __shared__ __align__(16) unsigned short in_s[32 * 264];   // [obs | masked act] -> hid overlay
  __shared__ __align__(16) unsigned short q_in[32 * 264];   // [obs | onh]
  __shared__ __align__(16) unsigned short act_bs[4 * 128];
  __shared__ float red[512];
  int tid = threadIdx.x, w = tid >> 6, lane = tid & 63;
  int lo = lane & 15, hi = lane >> 4;
  int row0 = blockIdx.x * 32, e0 = row0 >> 3;
  if (tid < 128) {
    float4 v = LD4(act + (size_t)e0 * 128 + (tid << 2));
    *(ushort4*)(act_bs + (tid << 2)) = f2bf4(v);
  }
  for (int i = tid; i < 1024; i += 512) {               // 32*128/4
    int r = i >> 5, c = (i & 31) << 2;
    float4 v = LD4(obs + (size_t)(row0 + r) * 128 + c);
    ushort4 u4 = f2bf4(v);
    *(ushort4*)(in_s + r * 264 + c) = u4;
    *(ushort4*)(q_in + r * 264 + c) = u4;
  }
  bf16x8 wf1[2][8], wf2[8];
#pragma unroll
  for (int cc = 0; cc < 2; cc++)
#pragma unroll
    for (int s = 0; s < 8; s++)
      wf1[cc][s] = *(const bf16x8*)(w1b + (size_t)(((2 * w + cc) * 8 + s) * 64 + lane) * 8);
#pragma unroll
  for (int s = 0; s < 8; s++)
    wf2[s] = *(const bf16x8*)(w2b + (size_t)((w * 8 + s) * 64 + lane) * 8);
  __syncthreads();
  for (int i = tid; i < 1024; i += 512) {
    int r = i >> 5, c = (i & 31) << 2;
    int j = c >> 4, ii = r & 7;
    ushort4 v = (j == ii) ? make_ushort4(0, 0, 0, 0)
                          : *(const ushort4*)(act_bs + (r >> 3) * 128 + c);
    *(ushort4*)(in_s + r * 264 + 128 + c) = v;
  }
  __syncthreads();
  // layer1: wave w -> cols [32w, 32w+32)
  f32x4 acc[2][2];
#pragma unroll
  for (int rt = 0; rt < 2; rt++) { acc[rt][0] = {0,0,0,0}; acc[rt][1] = {0,0,0,0}; }
#pragma unroll
  for (int s = 0; s < 8; s++)
#pragma unroll
    for (int rt = 0; rt < 2; rt++) {
      bf16x8 af = *(const bf16x8*)(in_s + (rt * 16 + lo) * 264 + s * 32 + hi * 8);
      acc[rt][0] = MFMA16(af, wf1[0][s], acc[rt][0]);
      acc[rt][1] = MFMA16(af, wf1[1][s], acc[rt][1]);
    }
  float b1a = b1[32 * w + lo], b1b = b1[32 * w + 16 + lo];
  __syncthreads();
#pragma unroll
  for (int rt = 0; rt < 2; rt++)
#pragma unroll
    for (int r = 0; r < 4; r++) {
      int rowl = rt * 16 + hi * 4 + r;
      in_s[rowl * 264 + 32 * w + lo]      = f2bf(fmaxf(acc[rt][0][r] + b1a, 0.f));
      in_s[rowl * 264 + 32 * w + 16 + lo] = f2bf(fmaxf(acc[rt][1][r] + b1b, 0.f));
    }
  __syncthreads();
  // layer2: wave w -> cols [16w, 16w+16)
  f32x4 acc2[2];
  acc2[0] = {0, 0, 0, 0}; acc2[1] = {0, 0, 0, 0};
#pragma unroll
  for (int s = 0; s < 8; s++)
#pragma unroll
    for (int rt = 0; rt < 2; rt++) {
      bf16x8 af = *(const bf16x8*)(in_s + (rt * 16 + lo) * 264 + s * 32 + hi * 8);
      acc2[rt] = MFMA16(af, wf2[s], acc2[rt]);
    }
  int col = 16 * w + lo;
  float b2c = b2[col];
  float ms = 0.f;
#pragma unroll
  for (int rt = 0; rt < 2; rt++)
#pragma unroll
    for (int r = 0; r < 4; r++) {
      int rowl = rt * 16 + hi * 4 + r;
      float v = acc2[rt][r] + b2c;
      q_in[rowl * 264 + 128 + col] = f2bf(v);
      float d = v - obsn[(size_t)(row0 + rowl) * 128 + col];
      ms = fmaf(d, d, ms);
    }
  __syncthreads();
  // query: c = w&3, rt = w>>2
  {
    int c = w & 3, rt = w >> 2;
    bf16x8 wf3[8];
#pragma unroll
    for (int s = 0; s < 8; s++)
      wf3[s] = *(const bf16x8*)(wqb + (size_t)((c * 8 + s) * 64 + lane) * 8);
    f32x4 aq = {0, 0, 0, 0};
#pragma unroll
    for (int s = 0; s < 8; s++) {
      bf16x8 af = *(const bf16x8*)(q_in + (rt * 16 + lo) * 264 + s * 32 + hi * 8);
      aq = MFMA16(af, wf3[s], aq);
    }
    float bqc = bq[16 * c + lo];
#pragma unroll
    for (int r = 0; r < 4; r++) {
      int row = row0 + rt * 16 + hi * 4 + r;
      qry[(size_t)row * 64 + 16 * c + lo] = aq[r] + bqc;
    }
  }
  red[tid] = ms;
  __syncthreads();
  for (int st = 256; st > 0; st >>= 1) {
    if (tid < st) red[tid] += red[tid + st];
    __syncthreads();
  }
  if (tid == 0) l2p[blockIdx.x] = red[0];
}

// fused key + value + attention (+ block0: loss finalize): 32 rows/block, 4 waves
__global__ __launch_bounds__(256) void k_kva(
    const float* __restrict__ h, const float* __restrict__ act,
    const float* __restrict__ ws, const float* __restrict__ bk,
    const float* __restrict__ bv1, const float* __restrict__ bv2,
    const float* __restrict__ qry, const float* __restrict__ l1p,
    const float* __restrict__ l2p, float* __restrict__ qout)
{
  __shared__ __align__(16) float in_s[32 * 80];
  __shared__ __align__(16) float hid_s[32 * 64];
  __shared__ __align__(16) float key_s[32 * 68];
  __shared__ float val_s[32 * 16];
  __shared__ float qs[4][64];
  __shared__ float red2[256];
  int tid = threadIdx.x, w = tid >> 6, lane = tid & 63;
  int row0 = blockIdx.x * 32;
  if (blockIdx.x == 0) {
    float s1 = l1p[tid] + l1p[tid + 256];
    float s2 = l2p[tid] + l2p[tid + 256];
    red2[tid] = s1;
    __syncthreads();
    for (int s = 128; s > 0; s >>= 1) {
      if (tid < s) red2[tid] += red2[tid + s];
      __syncthreads();
    }
    float S1 = red2[0];
    __syncthreads();
    red2[tid] = s2;
    __syncthreads();
    for (int s = 128; s > 0; s >>= 1) {
      if (tid < s) red2[tid] += red2[tid + s];
      __syncthreads();
    }
    if (tid == 0) {
      qout[DO_L1] = S1 * 7.f / 131072.f;
      qout[DO_L2] = red2[0] / 2097152.f;
    }
    __syncthreads();
  }
  for (int i = tid; i < 512; i += 256) {                 // 32*64/4 float4s
    int r = i >> 4, c = (i & 15) << 2;
    *(float4*)(in_s + r * 80 + c) = LD4(h + (size_t)(row0 + r) * 64 + c);
  }
  if (tid < 128) {                                       // 32*16/4
    int r = tid >> 2, c = (tid & 3) << 2;
    *(float4*)(in_s + r * 80 + 64 + c) = LD4(act + (size_t)(row0 + r) * 16 + c);
  }
  // prefetch this wave's 8 qry rows (pipelined independent loads)
  float qreg[8];
#pragma unroll
  for (int rr = 0; rr < 8; rr++)
    qreg[rr] = qry[(size_t)(row0 + w * 8 + rr) * 64 + lane];
  __syncthreads();
  const float* w1T = ws + T_WV1;
  const float* w2T = ws + T_WV2;
  const float* wkT = ws + T_WK;
  float acc[8];
#pragma unroll
  for (int r = 0; r < 8; r++) acc[r] = bv1[lane];
  for (int k = 0; k < 80; k += 4) {
    float b[4];
#pragma unroll
    for (int j = 0; j < 4; j++) b[j] = w1T[(k + j) * 64 + lane];
#pragma unroll
    for (int r = 0; r < 8; r++) {
      float4 a = LD4(in_s + (w * 8 + r) * 80 + k);
      acc[r] = fmaf(a.x, b[0], fmaf(a.y, b[1], fmaf(a.z, b[2], fmaf(a.w, b[3], acc[r]))));
    }
  }
#pragma unroll
  for (int r = 0; r < 8; r++) hid_s[(w * 8 + r) * 64 + lane] = fmaxf(acc[r], 0.f);
  float ka[8];
#pragma unroll
  for (int r = 0; r < 8; r++) ka[r] = bk[lane];
  for (int k = 0; k < 16; k += 4) {
    float b[4];
#pragma unroll
    for (int j = 0; j < 4; j++) b[j] = wkT[(k + j) * 64 + lane];
#pragma unroll
    for (int r = 0; r < 8; r++) {
      float4 a = LD4(in_s + (w * 8 + r) * 80 + 64 + k);
      ka[r] = fmaf(a.x, b[0], fmaf(a.y, b[1], fmaf(a.z, b[2], fmaf(a.w, b[3], ka[r]))));
    }
  }
#pragma unroll
  for (int r = 0; r < 8; r++) key_s[(w * 8 + r) * 68 + lane] = ka[r];
  int col = lane & 15, kq = lane >> 4;
  float a2[8] = {0, 0, 0, 0, 0, 0, 0, 0};
  for (int kk = 0; kk < 16; kk += 4) {
    int k = kq * 16 + kk;
    float b[4];
#pragma unroll
    for (int j = 0; j < 4; j++) b[j] = w2T[(k + j) * 16 + col];
#pragma unroll
    for (int r = 0; r < 8; r++) {
      float4 a = LD4(hid_s + (w * 8 + r) * 64 + k);
      a2[r] = fmaf(a.x, b[0], fmaf(a.y, b[1], fmaf(a.z, b[2], fmaf(a.w, b[3], a2[r]))));
    }
  }
#pragma unroll
  for (int r = 0; r < 8; r++) {
    a2[r] += __shfl_xor(a2[r], 16);
    a2[r] += __shfl_xor(a2[r], 32);
  }
  if (lane < 16) {
#pragma unroll
    for (int r = 0; r < 8; r++) val_s[(w * 8 + r) * 16 + col] = a2[r] + bv2[col];
  }
  int j = lane >> 3, p = lane & 7;
  for (int rr = 0; rr < 8; rr++) {
    int b = row0 + w * 8 + rr;
    qs[w][lane] = qreg[rr];
    const float* krow = key_s + (w * 8 + j) * 68;
    float s = 0.f;
#pragma unroll
    for (int t = 0; t < 8; t++) {
      int d = p * 8 + t;
      s = fmaf(qs[w][d], krow[d], s);
    }
    s += __shfl_xor(s, 1);
    s += __shfl_xor(s, 2);
    s += __shfl_xor(s, 4);
    float score = (j == rr) ? -1e9f : s * 0.125f;
    float sc[8];
    float m = -1e30f;
#pragma unroll
    for (int jj = 0; jj < 8; jj++) {
      sc[jj] = __shfl(score, jj * 8);
      m = fmaxf(m, sc[jj]);
    }
    float ssum = 0.f;
#pragma unroll
    for (int jj = 0; jj < 8; jj++) { sc[jj] = expf(sc[jj] - m); ssum += sc[jj]; }
    float inv = 1.f / ssum;
    int c = lane & 15, g = lane >> 4;
    const float* vb = val_s + w * 8 * 16;
    float outv = sc[g] * inv * vb[g * 16 + c] + sc[g + 4] * inv * vb[(g + 4) * 16 + c];
    outv += __shfl_xor(outv, 16);
    outv += __shfl_xor(outv, 32);
    if (lane < 16) qout[(size_t)b * 16 + lane] = outv;
  }
}

extern "C" void kernel_launch(void* const* d_in, const int* in_sizes, int n_in,
                              void* d_out, int out_size, void* d_ws, size_t ws_size,
                              hipStream_t stream) {
  const float* inputs   = (const float*)d_in[0];
  const float* hidden   = (const float*)d_in[1];
  const float* obs      = (const float*)d_in[2];
  const float* obs_next = (const float*)d_in[3];
  const int*   u        = (const int*)d_in[4];
  const float* fc1_w = (const float*)d_in[5];   const float* fc1_b = (const float*)d_in[6];
  const float* wih   = (const float*)d_in[7];   const float* bih   = (const float*)d_in[8];
  const float* whh   = (const float*)d_in[9];   const float* bhh   = (const float*)d_in[10];
  const float* tm_w1 = (const float*)d_in[11];  const float* tm_b1 = (const float*)d_in[12];
  const float* tm_w2 = (const float*)d_in[13];  const float* tm_b2 = (const float*)d_in[14];
  const float* wm_w1 = (const float*)d_in[15];  const float* wm_b1 = (const float*)d_in[16];
  const float* wm_w2 = (const float*)d_in[17];  const float* wm_b2 = (const float*)d_in[18];
  const float* wq_w  = (const float*)d_in[19];  const float* wq_b  = (const float*)d_in[20];
  const float* wk_w  = (const float*)d_in[21];  const float* wk_b  = (const float*)d_in[22];
  const float* wv1_w = (const float*)d_in[23];  const float* wv1_b = (const float*)d_in[24];
  const float* wv2_w = (const float*)d_in[25];  const float* wv2_b = (const float*)d_in[26];

  float* ws   = (float*)d_ws;
  unsigned short* wsu = (unsigned short*)d_ws;
  float* out  = (float*)d_out;
  float* hbuf = out + DO_H;

  PrepP p;
  const float* tsr[3] = {wk_w, wv1_w, wv2_w};
  int tO[3]  = {64, 64, 16};
  int tK[3]  = {16, 80, 64};
  int tOf[3] = {T_WK, T_WV1, T_WV2};
  for (int i = 0; i < 3; i++) { p.tsrc[i] = tsr[i]; p.tO[i] = tO[i]; p.tK[i] = tK[i]; p.tOff[i] = tOf[i]; }
  const float* ssr[8] = {wm_w1, wm_w2, wq_w, tm_w1, tm_w2, fc1_w, wih, whh};
  int sO[8]  = {256, 128, 64, 256, 16, 64, 192, 192};
  int sK[8]  = {256, 256, 256, 64, 256, 160, 64, 64};
  int sKs[8] = {256, 256, 256, 64, 256, 152, 64, 64};
  int sSt[8] = {256, 256, 256, 72, 256, 152, 64, 64};
  int sOf[8] = {B_WM1*2, B_WM2*2, B_WQ*2, B_TM1*2, B_TM2*2, B_FC1*2, B_WIH*2, B_WHH*2};
  for (int i = 0; i < 8; i++) {
    p.ssrc[i] = ssr[i]; p.sO[i] = sO[i]; p.sK[i] = sK[i];
    p.sKs[i] = sKs[i]; p.sSt[i] = sSt[i]; p.sOff[i] = sOf[i];
  }
  p.tm_w1 = tm_w1; p.tm_b1 = tm_b1;

  k_prep<<<160, 256, 0, stream>>>(p, ws, wsu);
  k_trunk<<<ROWS / 32, 512, 0, stream>>>(inputs, hidden,
      wsu + B_FC1*2, wsu + B_WIH*2, wsu + B_WHH*2, fc1_b, bih, bhh, hbuf);
  k_tm<<<ROWS / 32, 512, 0, stream>>>(hbuf, wsu + B_TM1*2, wsu + B_TM2*2,
      ws + TMB, tm_b2, u, ws + O_ACT, ws + O_L1P);
  k_wm<<<ROWS / 32, 512, 0, stream>>>(obs, ws + O_ACT,
      wsu + B_WM1*2, wsu + B_WM2*2, wsu + B_WQ*2, wm_b1, wm_b2, wq_b, obs_next,
      ws + O_QRY, ws + O_L2P);
  k_kva<<<ROWS / 32, 256, 0, stream>>>(hbuf, ws + O_ACT, ws, wk_b, wv1_b, wv2_b,
      ws + O_QRY, ws + O_L1P, ws + O_L2P, out);
}

// Round 12
// 52.625 us; speedup vs baseline: 1.4904x; 1.0768x over previous
//
#include <hip/hip_runtime.h>
#include <math.h>

#define E_NUM 2048
#define A_N   8
#define ROWS  (E_NUM*A_N)   // 16384
#define TRUNK_BLOCKS 512
#define TRUNK_EXTRA  108    // 24 transpose + 80 swizzle + 4 tmB

typedef __attribute__((ext_vector_type(8))) short bf16x8;
typedef __attribute__((ext_vector_type(4))) float f32x4;

__device__ __forceinline__ unsigned short f2bf(float x) {
  unsigned int u = __float_as_uint(x);
  return (unsigned short)((u + 0x7FFFu + ((u >> 16) & 1u)) >> 16);
}
__device__ __forceinline__ ushort4 f2bf4(float4 v) {
  return make_ushort4(f2bf(v.x), f2bf(v.y), f2bf(v.z), f2bf(v.w));
}
__device__ __forceinline__ float bf2f(unsigned short u) {
  return __uint_as_float(((unsigned int)u) << 16);
}
#define MFMA16(a,b,c) __builtin_amdgcn_mfma_f32_16x16x32_bf16(a,b,c,0,0,0)

// ---- ws layout (float offsets) ----
#define T_WK   0         // 16*64 f32 transposed
#define T_WV1  1024      // 80*64
#define T_WV2  6144      // 64*16
#define TMB    7168      // 8*256 f32
#define B_WM1  9216      // 256x256 bf16 frag-major (32768 fl)
#define B_WM2  41984     // 128x256 (16384 fl)
#define B_WQ   58368     // 64x256 (8192 fl)
#define B_TM1  66560     // 256x64 (8192 fl)
#define B_TM2  74752     // 16x256 (2048 fl)
#define B_FC1  76800     // 64x160 (5120 fl)
#define B_WIH  81920     // 192x64 (6144 fl)
#define B_WHH  88064     // 192x64 (6144 fl)
#define O_ACT  94208     // 16384*16 f32
#define O_QRY  356352    // 16384*64 bf16 (524288 ushorts = 262144 fl)
#define O_L1P  1404928   // 512
#define O_L2P  1405440   // 512

// d_out: q_reflect [0,262144) ; h ; loss1 ; loss2
#define DO_H   262144
#define DO_L1  1310720
#define DO_L2  1310721

#define LD4(p) (*(const float4*)(p))

struct PrepP {
  const float* tsrc[3]; int tO[3], tK[3], tOff[3];
  const float* ssrc[8]; int sO[8], sK[8], sKs[8], sSt[8], sOff[8]; // sOff in ushort units
  const float* tm_w1; const float* tm_b1;
};

// 48 blocks: bf16 frag swizzle of fc1/wih/whh only (what k_trunk needs)
__global__ __launch_bounds__(256) void k_prep(PrepP p, float* __restrict__ ws,
                                              unsigned short* __restrict__ wsu) {
  int bid = blockIdx.x;
  int m = 5 + (bid >> 4), sub = bid & 15;
  const float* src = p.ssrc[m];
  unsigned short* dst = wsu + p.sOff[m];
  int K = p.sK[m], Ks = p.sKs[m], stride = p.sSt[m], n = p.sO[m] * K, S = K >> 5;
  for (int f = sub * 256 + threadIdx.x; f < n; f += 16 * 256) {
    int j = f & 7, l = (f >> 3) & 63, rest = f >> 9;
    int s = rest % S, c = rest / S;
    int row = c * 16 + (l & 15), col = s * 32 + ((l >> 4) << 3) + j;
    dst[f] = (col < Ks) ? f2bf(src[row * stride + col]) : (unsigned short)0;
  }
}

// fc1 + GRU (MFMA, weight-stationary): 32 rows/block, 8 waves (512 thr)
// blocks >= TRUNK_BLOCKS: remaining prep (transposes, wm/tm/wq swizzles, tmB)
__global__ __launch_bounds__(512) void k_trunk(
    const float* __restrict__ inp, const float* __restrict__ hin,
    const unsigned short* __restrict__ fc1bf, const unsigned short* __restrict__ wihbf,
    const unsigned short* __restrict__ whhbf,
    const float* __restrict__ fc1_b, const float* __restrict__ bih, const float* __restrict__ bhh,
    float* __restrict__ hout, PrepP p, float* __restrict__ ws_f,
    unsigned short* __restrict__ wsu)
{
  __shared__ __align__(16) unsigned short in_b[32 * 168];
  __shared__ __align__(16) unsigned short x_b[32 * 72];
  __shared__ __align__(16) unsigned short h_b[32 * 72];
  int tid = threadIdx.x, w = tid >> 6, lane = tid & 63;
  int lo = lane & 15, hi = lane >> 4;

  if (blockIdx.x >= TRUNK_BLOCKS) {
    int eb = blockIdx.x - TRUNK_BLOCKS;
    if (eb < 24) {
      int b = eb >> 3, sl = eb & 7;
      const float* s = p.tsrc[b];
      float* d = ws_f + p.tOff[b];
      int O = p.tO[b], K = p.tK[b], n = O * K;
      for (int i = sl * 512 + tid; i < n; i += 8 * 512) {
        int o = i / K, k = i - o * K;
        d[k * O + o] = s[i];
      }
    } else if (eb < 104) {
      int q = eb - 24, m = q >> 4, sub = q & 15;   // m in 0..4 (wm1,wm2,wq,tm1,tm2)
      const float* src = p.ssrc[m];
      unsigned short* dst = wsu + p.sOff[m];
      int K = p.sK[m], Ks = p.sKs[m], stride = p.sSt[m], n = p.sO[m] * K, S = K >> 5;
      for (int f = sub * 512 + tid; f < n; f += 16 * 512) {
        int j = f & 7, l = (f >> 3) & 63, rest = f >> 9;
        int s = rest % S, c = rest / S;
        int row = c * 16 + (l & 15), col = s * 32 + ((l >> 4) << 3) + j;
        dst[f] = (col < Ks) ? f2bf(src[row * stride + col]) : (unsigned short)0;
      }
    } else {
      int i = (eb - 104) * 512 + tid;   // 4 blocks x 512 = 2048
      int j = i >> 8, o = i & 255;
      ws_f[TMB + i] = p.tm_b1[o] + p.tm_w1[o * 72 + 64 + j];
    }
    return;
  }

  int row0 = blockIdx.x * 32;
  int c = w & 3, rt = w >> 2;

  for (int i = tid; i < 1216; i += 512) {              // 32*152/4
    int e = i << 2;
    int r = e / 152, cc = e - r * 152;
    float4 v = LD4(inp + (size_t)(row0 + r) * 152 + cc);
    *(ushort4*)(in_b + r * 168 + cc) = f2bf4(v);
  }
  if (tid < 256) { int r = tid >> 3, cc = tid & 7; in_b[r * 168 + 152 + cc] = 0; }
  {
    int r = tid >> 4, cc = (tid & 15) << 2;            // 512 float4s, one per thread
    float4 v = LD4(hin + (size_t)(row0 + r) * 64 + cc);
    *(ushort4*)(h_b + r * 72 + cc) = f2bf4(v);
  }
  __syncthreads();

  bf16x8 wf1[5];
#pragma unroll
  for (int s = 0; s < 5; s++)
    wf1[s] = *(const bf16x8*)(fc1bf + (size_t)((c * 5 + s) * 64 + lane) * 8);
  f32x4 acc = {0, 0, 0, 0};
#pragma unroll
  for (int s = 0; s < 5; s++) {
    bf16x8 af = *(const bf16x8*)(in_b + (rt * 16 + lo) * 168 + s * 32 + hi * 8);
    acc = MFMA16(af, wf1[s], acc);
  }
  float fb = fc1_b[16 * c + lo];
#pragma unroll
  for (int r = 0; r < 4; r++)
    x_b[(rt * 16 + hi * 4 + r) * 72 + 16 * c + lo] = f2bf(fmaxf(acc[r] + fb, 0.f));
  __syncthreads();

  bf16x8 wfi[3][2], wfh[3][2];
#pragma unroll
  for (int t = 0; t < 3; t++)
#pragma unroll
    for (int s = 0; s < 2; s++) {
      int chunk = c + 4 * t;
      wfi[t][s] = *(const bf16x8*)(wihbf + (size_t)((chunk * 2 + s) * 64 + lane) * 8);
      wfh[t][s] = *(const bf16x8*)(whhbf + (size_t)((chunk * 2 + s) * 64 + lane) * 8);
    }
  f32x4 ai[3], ah[3];
#pragma unroll
  for (int t = 0; t < 3; t++) { ai[t] = {0,0,0,0}; ah[t] = {0,0,0,0}; }
#pragma unroll
  for (int s = 0; s < 2; s++) {
    bf16x8 ax  = *(const bf16x8*)(x_b + (rt * 16 + lo) * 72 + s * 32 + hi * 8);
    bf16x8 ahv = *(const bf16x8*)(h_b + (rt * 16 + lo) * 72 + s * 32 + hi * 8);
#pragma unroll
    for (int t = 0; t < 3; t++) {
      ai[t] = MFMA16(ax,  wfi[t][s], ai[t]);
      ah[t] = MFMA16(ahv, wfh[t][s], ah[t]);
    }
  }
  int col = 16 * c + lo;
  float b_ir = bih[col],       b_hr = bhh[col];
  float b_iz = bih[64 + col],  b_hz = bhh[64 + col];
  float b_in = bih[128 + col], b_hn = bhh[128 + col];
#pragma unroll
  for (int r = 0; r < 4; r++) {
    size_t grow = (size_t)(row0 + rt * 16 + hi * 4 + r);
    float rg = 1.f / (1.f + expf(-(ai[0][r] + b_ir + ah[0][r] + b_hr)));
    float zg = 1.f / (1.f + expf(-(ai[1][r] + b_iz + ah[1][r] + b_hz)));
    float ng = tanhf(fmaf(rg, ah[2][r] + b_hn, ai[2][r] + b_in));
    float h0 = hin[grow * 64 + col];
    hout[grow * 64 + col] = (1.f - zg) * ng + zg * h0;
  }
}

// teammate MLP + CE (MFMA, weight-stationary): 32 rows/block, 8 waves
__global__ __launch_bounds__(512) void k_tm(
    const float* __restrict__ h,
    const unsigned short* __restrict__ w1b, const unsigned short* __restrict__ w2b,
    const float* __restrict__ tmB, const float* __restrict__ b2,
    const int* __restrict__ u,
    float* __restrict__ act, float* __restrict__ l1p)
{
  __shared__ __align__(16) unsigned short in_s[32 * 72];
  __shared__ __align__(16) unsigned short hid_s[32 * 264];
  __shared__ float red[512];
  int tid = threadIdx.x, w = tid >> 6, lane = tid & 63;
  int lo = lane & 15, hi = lane >> 4;
  int row0 = blockIdx.x * 32;
  {
    int r = tid >> 4, cc = (tid & 15) << 2;            // 512 float4s
    float4 v = LD4(h + (size_t)(row0 + r) * 64 + cc);
    *(ushort4*)(in_s + r * 72 + cc) = f2bf4(v);
  }
  bf16x8 wf1[2][2];
#pragma unroll
  for (int cc = 0; cc < 2; cc++)
#pragma unroll
    for (int s = 0; s < 2; s++)
      wf1[cc][s] = *(const bf16x8*)(w1b + (size_t)(((2 * w + cc) * 2 + s) * 64 + lane) * 8);
  __syncthreads();
  f32x4 acc[2][2];
#pragma unroll
  for (int rt = 0; rt < 2; rt++) { acc[rt][0] = {0,0,0,0}; acc[rt][1] = {0,0,0,0}; }
#pragma unroll
  for (int s = 0; s < 2; s++)
#pragma unroll
    for (int rt = 0; rt < 2; rt++) {
      bf16x8 af = *(const bf16x8*)(in_s + (rt * 16 + lo) * 72 + s * 32 + hi * 8);
      acc[rt][0] = MFMA16(af, wf1[0][s], acc[rt][0]);
      acc[rt][1] = MFMA16(af, wf1[1][s], acc[rt][1]);
    }
#pragma unroll
  for (int rt = 0; rt < 2; rt++)
#pragma unroll
    for (int r = 0; r < 4; r++) {
      int rowl = rt * 16 + hi * 4 + r, j = (hi * 4 + r) & 7;
      float v0 = acc[rt][0][r] + tmB[j * 256 + 32 * w + lo];
      float v1 = acc[rt][1][r] + tmB[j * 256 + 32 * w + 16 + lo];
      hid_s[rowl * 264 + 32 * w + lo]      = f2bf(fmaxf(v0, 0.f));
      hid_s[rowl * 264 + 32 * w + 16 + lo] = f2bf(fmaxf(v1, 0.f));
    }
  __syncthreads();
  float ces = 0.f;
  if (w < 2) {
    bf16x8 wf2[8];
#pragma unroll
    for (int s = 0; s < 8; s++)
      wf2[s] = *(const bf16x8*)(w2b + (size_t)(s * 64 + lane) * 8);
    f32x4 a2 = {0, 0, 0, 0};
#pragma unroll
    for (int s = 0; s < 8; s++) {
      bf16x8 af = *(const bf16x8*)(hid_s + (w * 16 + lo) * 264 + s * 32 + hi * 8);
      a2 = MFMA16(af, wf2[s], a2);
    }
    float b2c = b2[lo];
#pragma unroll
    for (int r = 0; r < 4; r++) {
      int rowl = w * 16 + hi * 4 + r;
      float v = a2[r] + b2c;
      act[(size_t)(row0 + rowl) * 16 + lo] = v;
      float m = v;
      m = fmaxf(m, __shfl_xor(m, 1));
      m = fmaxf(m, __shfl_xor(m, 2));
      m = fmaxf(m, __shfl_xor(m, 4));
      m = fmaxf(m, __shfl_xor(m, 8));
      float se = expf(v - m);
      se += __shfl_xor(se, 1);
      se += __shfl_xor(se, 2);
      se += __shfl_xor(se, 4);
      se += __shfl_xor(se, 8);
      int lbl = u[row0 + rowl];
      float vl = __shfl(v, (lane & 48) + lbl);
      if (lo == 0) ces += -(vl - m - logf(se));
    }
  }
  red[tid] = ces;
  __syncthreads();
  for (int st = 256; st > 0; st >>= 1) {
    if (tid < st) red[tid] += red[tid + st];
    __syncthreads();
  }
  if (tid == 0) l1p[blockIdx.x] = red[0];
}

// world model + MSE + query: 32 rows/block, 8 waves ; qry written bf16
__global__ __launch_bounds__(512) void k_wm(
    const float* __restrict__ obs, const float* __restrict__ act,
    const unsigned short* __restrict__ w1b, const unsigned short* __restrict__ w2b,
    const unsigned short* __restrict__ wqb,
    const float* __restrict__ b1, const float* __restrict__ b2, const float* __restrict__ bq,
    const float* __restrict__ obsn,
    unsigned short* __restrict__ qryb, float* __restrict__ l2p)
{
  __shared__ __align__(16) unsigned short in_s[32 * 264];   // [obs | masked act] -> hid overlay
  __shared__ __align__(16) unsigned short q_in[32 * 264];   // [obs | onh]
  __shared__ __align__(16) unsigned short act_bs[4 * 128];
  __shared__ float red[512];
  int tid = threadIdx.x, w = tid >> 6, lane = tid & 63;
  int lo = lane & 15, hi = lane >> 4;
  int row0 = blockIdx.x * 32, e0 = row0 >> 3;
  if (tid < 128) {
    float4 v = LD4(act + (size_t)e0 * 128 + (tid << 2));
    *(ushort4*)(act_bs + (tid << 2)) = f2bf4(v);
  }
  for (int i = tid; i < 1024; i += 512) {               // 32*128/4
    int r = i >> 5, c = (i & 31) << 2;
    float4 v = LD4(obs + (size_t)(row0 + r) * 128 + c);
    ushort4 u4 = f2bf4(v);
    *(ushort4*)(in_s + r * 264 + c) = u4;
    *(ushort4*)(q_in + r * 264 + c) = u4;
  }
  bf16x8 wf1[2][8], wf2[8];
#pragma unroll
  for (int cc = 0; cc < 2; cc++)
#pragma unroll
    for (int s = 0; s < 8; s++)
      wf1[cc][s] = *(const bf16x8*)(w1b + (size_t)(((2 * w + cc) * 8 + s) * 64 + lane) * 8);
#pragma unroll
  for (int s = 0; s < 8; s++)
    wf2[s] = *(const bf16x8*)(w2b + (size_t)((w * 8 + s) * 64 + lane) * 8);
  __syncthreads();
  for (int i = tid; i < 1024; i += 512) {
    int r = i >> 5, c = (i & 31) << 2;
    int j = c >> 4, ii = r & 7;
    ushort4 v = (j == ii) ? make_ushort4(0, 0, 0, 0)
                          : *(const ushort4*)(act_bs + (r >> 3) * 128 + c);
    *(ushort4*)(in_s + r * 264 + 128 + c) = v;
  }
  __syncthreads();
  // layer1: wave w -> cols [32w, 32w+32)
  f32x4 acc[2][2];
#pragma unroll
  for (int rt = 0; rt < 2; rt++) { acc[rt][0] = {0,0,0,0}; acc[rt][1] = {0,0,0,0}; }
#pragma unroll
  for (int s = 0; s < 8; s++)
#pragma unroll
    for (int rt = 0; rt < 2; rt++) {
      bf16x8 af = *(const bf16x8*)(in_s + (rt * 16 + lo) * 264 + s * 32 + hi * 8);
      acc[rt][0] = MFMA16(af, wf1[0][s], acc[rt][0]);
      acc[rt][1] = MFMA16(af, wf1[1][s], acc[rt][1]);
    }
  float b1a = b1[32 * w + lo], b1b = b1[32 * w + 16 + lo];
  __syncthreads();
#pragma unroll
  for (int rt = 0; rt < 2; rt++)
#pragma unroll
    for (int r = 0; r < 4; r++) {
      int rowl = rt * 16 + hi * 4 + r;
      in_s[rowl * 264 + 32 * w + lo]      = f2bf(fmaxf(acc[rt][0][r] + b1a, 0.f));
      in_s[rowl * 264 + 32 * w + 16 + lo] = f2bf(fmaxf(acc[rt][1][r] + b1b, 0.f));
    }
  __syncthreads();
  // layer2: wave w -> cols [16w, 16w+16)
  f32x4 acc2[2];
  acc2[0] = {0, 0, 0, 0}; acc2[1] = {0, 0, 0, 0};
#pragma unroll
  for (int s = 0; s < 8; s++)
#pragma unroll
    for (int rt = 0; rt < 2; rt++) {
      bf16x8 af = *(const bf16x8*)(in_s + (rt * 16 + lo) * 264 + s * 32 + hi * 8);
      acc2[rt] = MFMA16(af, wf2[s], acc2[rt]);
    }
  int col = 16 * w + lo;
  float b2c = b2[col];
  float ms = 0.f;
#pragma unroll
  for (int rt = 0; rt < 2; rt++)
#pragma unroll
    for (int r = 0; r < 4; r++) {
      int rowl = rt * 16 + hi * 4 + r;
      float v = acc2[rt][r] + b2c;
      q_in[rowl * 264 + 128 + col] = f2bf(v);
      float d = v - obsn[(size_t)(row0 + rowl) * 128 + col];
      ms = fmaf(d, d, ms);
    }
  __syncthreads();
  // query: c = w&3, rt = w>>2 -> bf16 qry
  {
    int c = w & 3, rt = w >> 2;
    bf16x8 wf3[8];
#pragma unroll
    for (int s = 0; s < 8; s++)
      wf3[s] = *(const bf16x8*)(wqb + (size_t)((c * 8 + s) * 64 + lane) * 8);
    f32x4 aq = {0, 0, 0, 0};
#pragma unroll
    for (int s = 0; s < 8; s++) {
      bf16x8 af = *(const bf16x8*)(q_in + (rt * 16 + lo) * 264 + s * 32 + hi * 8);
      aq = MFMA16(af, wf3[s], aq);
    }
    float bqc = bq[16 * c + lo];
#pragma unroll
    for (int r = 0; r < 4; r++) {
      int row = row0 + rt * 16 + hi * 4 + r;
      qryb[(size_t)row * 64 + 16 * c + lo] = f2bf(aq[r] + bqc);
    }
  }
  red[tid] = ms;
  __syncthreads();
  for (int st = 256; st > 0; st >>= 1) {
    if (tid < st) red[tid] += red[tid + st];
    __syncthreads();
  }
  if (tid == 0) l2p[blockIdx.x] = red[0];
}

// fused key + value + attention (+ block0: loss finalize): 32 rows/block, 4 waves
__global__ __launch_bounds__(256) void k_kva(
    const float* __restrict__ h, const float* __restrict__ act,
    const float* __restrict__ ws, const float* __restrict__ bk,
    const float* __restrict__ bv1, const float* __restrict__ bv2,
    const unsigned short* __restrict__ qryb, const float* __restrict__ l1p,
    const float* __restrict__ l2p, float* __restrict__ qout)
{
  __shared__ __align__(16) float in_s[32 * 80];
  __shared__ __align__(16) float hid_s[32 * 64];
  __shared__ __align__(16) float key_s[32 * 68];
  __shared__ float val_s[32 * 16];
  __shared__ float qs[4][64];
  __shared__ float red2[256];
  int tid = threadIdx.x, w = tid >> 6, lane = tid & 63;
  int row0 = blockIdx.x * 32;
  if (blockIdx.x == 0) {
    float s1 = l1p[tid] + l1p[tid + 256];
    float s2 = l2p[tid] + l2p[tid + 256];
    red2[tid] = s1;
    __syncthreads();
    for (int s = 128; s > 0; s >>= 1) {
      if (tid < s) red2[tid] += red2[tid + s];
      __syncthreads();
    }
    float S1 = red2[0];
    __syncthreads();
    red2[tid] = s2;
    __syncthreads();
    for (int s = 128; s > 0; s >>= 1) {
      if (tid < s) red2[tid] += red2[tid + s];
      __syncthreads();
    }
    if (tid == 0) {
      qout[DO_L1] = S1 * 7.f / 131072.f;
      qout[DO_L2] = red2[0] / 2097152.f;
    }
    __syncthreads();
  }
  for (int i = tid; i < 512; i += 256) {                 // 32*64/4 float4s
    int r = i >> 4, c = (i & 15) << 2;
    *(float4*)(in_s + r * 80 + c) = LD4(h + (size_t)(row0 + r) * 64 + c);
  }
  if (tid < 128) {                                       // 32*16/4
    int r = tid >> 2, c = (tid & 3) << 2;
    *(float4*)(in_s + r * 80 + 64 + c) = LD4(act + (size_t)(row0 + r) * 16 + c);
  }
  // prefetch this wave's 8 qry rows (bf16 -> f32)
  float qreg[8];
#pragma unroll
  for (int rr = 0; rr < 8; rr++)
    qreg[rr] = bf2f(qryb[(size_t)(row0 + w * 8 + rr) * 64 + lane]);
  __syncthreads();
  const float* w1T = ws + T_WV1;
  const float* w2T = ws + T_WV2;
  const float* wkT = ws + T_WK;
  float acc[8];
#pragma unroll
  for (int r = 0; r < 8; r++) acc[r] = bv1[lane];
  for (int k = 0; k < 80; k += 4) {
    float b[4];
#pragma unroll
    for (int j = 0; j < 4; j++) b[j] = w1T[(k + j) * 64 + lane];
#pragma unroll
    for (int r = 0; r < 8; r++) {
      float4 a = LD4(in_s + (w * 8 + r) * 80 + k);
      acc[r] = fmaf(a.x, b[0], fmaf(a.y, b[1], fmaf(a.z, b[2], fmaf(a.w, b[3], acc[r]))));
    }
  }
#pragma unroll
  for (int r = 0; r < 8; r++) hid_s[(w * 8 + r) * 64 + lane] = fmaxf(acc[r], 0.f);
  float ka[8];
#pragma unroll
  for (int r = 0; r < 8; r++) ka[r] = bk[lane];
  for (int k = 0; k < 16; k += 4) {
    float b[4];
#pragma unroll
    for (int j = 0; j < 4; j++) b[j] = wkT[(k + j) * 64 + lane];
#pragma unroll
    for (int r = 0; r < 8; r++) {
      float4 a = LD4(in_s + (w * 8 + r) * 80 + 64 + k);
      ka[r] = fmaf(a.x, b[0], fmaf(a.y, b[1], fmaf(a.z, b[2], fmaf(a.w, b[3], ka[r]))));
    }
  }
#pragma unroll
  for (int r = 0; r < 8; r++) key_s[(w * 8 + r) * 68 + lane] = ka[r];
  int col = lane & 15, kq = lane >> 4;
  float a2[8] = {0, 0, 0, 0, 0, 0, 0, 0};
  for (int kk = 0; kk < 16; kk += 4) {
    int k = kq * 16 + kk;
    float b[4];
#pragma unroll
    for (int j = 0; j < 4; j++) b[j] = w2T[(k + j) * 16 + col];
#pragma unroll
    for (int r = 0; r < 8; r++) {
      float4 a = LD4(hid_s + (w * 8 + r) * 64 + k);
      a2[r] = fmaf(a.x, b[0], fmaf(a.y, b[1], fmaf(a.z, b[2], fmaf(a.w, b[3], a2[r]))));
    }
  }
#pragma unroll
  for (int r = 0; r < 8; r++) {
    a2[r] += __shfl_xor(a2[r], 16);
    a2[r] += __shfl_xor(a2[r], 32);
  }
  if (lane < 16) {
#pragma unroll
    for (int r = 0; r < 8; r++) val_s[(w * 8 + r) * 16 + col] = a2[r] + bv2[col];
  }
  int j = lane >> 3, p = lane & 7;
  for (int rr = 0; rr < 8; rr++) {
    int b = row0 + w * 8 + rr;
    qs[w][lane] = qreg[rr];
    const float* krow = key_s + (w * 8 + j) * 68;
    float s = 0.f;
#pragma unroll
    for (int t = 0; t < 8; t++) {
      int d = p * 8 + t;
      s = fmaf(qs[w][d], krow[d], s);
    }
    s += __shfl_xor(s, 1);
    s += __shfl_xor(s, 2);
    s += __shfl_xor(s, 4);
    float score = (j == rr) ? -1e9f : s * 0.125f;
    float sc[8];
    float m = -1e30f;
#pragma unroll
    for (int jj = 0; jj < 8; jj++) {
      sc[jj] = __shfl(score, jj * 8);
      m = fmaxf(m, sc[jj]);
    }
    float ssum = 0.f;
#pragma unroll
    for (int jj = 0; jj < 8; jj++) { sc[jj] = expf(sc[jj] - m); ssum += sc[jj]; }
    float inv = 1.f / ssum;
    int c = lane & 15, g = lane >> 4;
    const float* vb = val_s + w * 8 * 16;
    float outv = sc[g] * inv * vb[g * 16 + c] + sc[g + 4] * inv * vb[(g + 4) * 16 + c];
    outv += __shfl_xor(outv, 16);
    outv += __shfl_xor(outv, 32);
    if (lane < 16) qout[(size_t)b * 16 + lane] = outv;
  }
}

extern "C" void kernel_launch(void* const* d_in, const int* in_sizes, int n_in,
                              void* d_out, int out_size, void* d_ws, size_t ws_size,
                              hipStream_t stream) {
  const float* inputs   = (const float*)d_in[0];
  const float* hidden   = (const float*)d_in[1];
  const float* obs      = (const float*)d_in[2];
  const float* obs_next = (const float*)d_in[3];
  const int*   u        = (const int*)d_in[4];
  const float* fc1_w = (const float*)d_in[5];   const float* fc1_b = (const float*)d_in[6];
  const float* wih   = (const float*)d_in[7];   const float* bih   = (const float*)d_in[8];
  const float* whh   = (const float*)d_in[9];   const float* bhh   = (const float*)d_in[10];
  const float* tm_w1 = (const float*)d_in[11];  const float* tm_b1 = (const float*)d_in[12];
  const float* tm_w2 = (const float*)d_in[13];  const float* tm_b2 = (const float*)d_in[14];
  const float* wm_w1 = (const float*)d_in[15];  const float* wm_b1 = (const float*)d_in[16];
  const float* wm_w2 = (const float*)d_in[17];  const float* wm_b2 = (const float*)d_in[18];
  const float* wq_w  = (const float*)d_in[19];  const float* wq_b  = (const float*)d_in[20];
  const float* wk_w  = (const float*)d_in[21];  const float* wk_b  = (const float*)d_in[22];
  const float* wv1_w = (const float*)d_in[23];  const float* wv1_b = (const float*)d_in[24];
  const float* wv2_w = (const float*)d_in[25];  const float* wv2_b = (const float*)d_in[26];

  float* ws   = (float*)d_ws;
  unsigned short* wsu = (unsigned short*)d_ws;
  float* out  = (float*)d_out;
  float* hbuf = out + DO_H;

  PrepP p;
  const float* tsr[3] = {wk_w, wv1_w, wv2_w};
  int tO[3]  = {64, 64, 16};
  int tK[3]  = {16, 80, 64};
  int tOf[3] = {T_WK, T_WV1, T_WV2};
  for (int i = 0; i < 3; i++) { p.tsrc[i] = tsr[i]; p.tO[i] = tO[i]; p.tK[i] = tK[i]; p.tOff[i] = tOf[i]; }
  const float* ssr[8] = {wm_w1, wm_w2, wq_w, tm_w1, tm_w2, fc1_w, wih, whh};
  int sO[8]  = {256, 128, 64, 256, 16, 64, 192, 192};
  int sK[8]  = {256, 256, 256, 64, 256, 160, 64, 64};
  int sKs[8] = {256, 256, 256, 64, 256, 152, 64, 64};
  int sSt[8] = {256, 256, 256, 72, 256, 152, 64, 64};
  int sOf[8] = {B_WM1*2, B_WM2*2, B_WQ*2, B_TM1*2, B_TM2*2, B_FC1*2, B_WIH*2, B_WHH*2};
  for (int i = 0; i < 8; i++) {
    p.ssrc[i] = ssr[i]; p.sO[i] = sO[i]; p.sK[i] = sK[i];
    p.sKs[i] = sKs[i]; p.sSt[i] = sSt[i]; p.sOff[i] = sOf[i];
  }
  p.tm_w1 = tm_w1; p.tm_b1 = tm_b1;

  k_prep<<<48, 256, 0, stream>>>(p, ws, wsu);
  k_trunk<<<TRUNK_BLOCKS + TRUNK_EXTRA, 512, 0, stream>>>(inputs, hidden,
      wsu + B_FC1*2, wsu + B_WIH*2, wsu + B_WHH*2, fc1_b, bih, bhh, hbuf, p, ws, wsu);
  k_tm<<<ROWS / 32, 512, 0, stream>>>(hbuf, wsu + B_TM1*2, wsu + B_TM2*2,
      ws + TMB, tm_b2, u, ws + O_ACT, ws + O_L1P);
  k_wm<<<ROWS / 32, 512, 0, stream>>>(obs, ws + O_ACT,
      wsu + B_WM1*2, wsu + B_WM2*2, wsu + B_WQ*2, wm_b1, wm_b2, wq_b, obs_next,
      wsu + O_QRY * 2, ws + O_L2P);
  k_kva<<<ROWS / 32, 256, 0, stream>>>(hbuf, ws + O_ACT, ws, wk_b, wv1_b, wv2_b,
      wsu + O_QRY * 2, ws + O_L1P, ws + O_L2P, out);
}

// Round 13
// 49.234 us; speedup vs baseline: 1.5931x; 1.0689x over previous
//
#include <hip/hip_runtime.h>
#include <math.h>

#define E_NUM 2048
#define A_N   8
#define ROWS  (E_NUM*A_N)   // 16384
#define TRUNK_BLOCKS 512
#define TRUNK_EXTRA  108    // 24 transpose + 80 swizzle + 4 tmB

typedef __attribute__((ext_vector_type(8))) short bf16x8;
typedef __attribute__((ext_vector_type(4))) float f32x4;

__device__ __forceinline__ unsigned short f2bf(float x) {
  unsigned int u = __float_as_uint(x);
  return (unsigned short)((u + 0x7FFFu + ((u >> 16) & 1u)) >> 16);
}
__device__ __forceinline__ ushort4 f2bf4(float4 v) {
  return make_ushort4(f2bf(v.x), f2bf(v.y), f2bf(v.z), f2bf(v.w));
}
__device__ __forceinline__ float bf2f(unsigned short u) {
  return __uint_as_float(((unsigned int)u) << 16);
}
#define MFMA16(a,b,c) __builtin_amdgcn_mfma_f32_16x16x32_bf16(a,b,c,0,0,0)

// ---- ws layout (float offsets) ----
#define T_WK   0         // 16*64 f32 transposed
#define T_WV1  1024      // 80*64
#define T_WV2  6144      // 64*16
#define TMB    7168      // 8*256 f32
#define B_WM1  9216      // 256x256 bf16 frag-major (32768 fl)
#define B_WM2  41984     // 128x256 (16384 fl)
#define B_WQ   58368     // 64x256 (8192 fl)
#define B_TM1  66560     // 256x64 (8192 fl)
#define B_TM2  74752     // 16x256 (2048 fl)
#define B_FC1  76800     // 64x160 (5120 fl)
#define B_WIH  81920     // 192x64 (6144 fl)
#define B_WHH  88064     // 192x64 (6144 fl)
#define O_ACT  94208     // 16384*16 f32
#define O_QRY  356352    // 16384*64 bf16 (524288 ushorts = 262144 fl)
#define O_L1P  1404928   // 512
#define O_L2P  1405440   // 512

// d_out: q_reflect [0,262144) ; h ; loss1 ; loss2
#define DO_H   262144
#define DO_L1  1310720
#define DO_L2  1310721

#define LD4(p) (*(const float4*)(p))

struct PrepP {
  const float* tsrc[3]; int tO[3], tK[3], tOff[3];
  const float* ssrc[8]; int sO[8], sK[8], sKs[8], sSt[8], sOff[8]; // sOff in ushort units
  const float* tm_w1; const float* tm_b1;
};

// 48 blocks: bf16 frag swizzle of fc1/wih/whh only (what k_trunk needs)
__global__ __launch_bounds__(256) void k_prep(PrepP p, float* __restrict__ ws,
                                              unsigned short* __restrict__ wsu) {
  int bid = blockIdx.x;
  int m = 5 + (bid >> 4), sub = bid & 15;
  const float* src = p.ssrc[m];
  unsigned short* dst = wsu + p.sOff[m];
  int K = p.sK[m], Ks = p.sKs[m], stride = p.sSt[m], n = p.sO[m] * K, S = K >> 5;
  for (int f = sub * 256 + threadIdx.x; f < n; f += 16 * 256) {
    int j = f & 7, l = (f >> 3) & 63, rest = f >> 9;
    int s = rest % S, c = rest / S;
    int row = c * 16 + (l & 15), col = s * 32 + ((l >> 4) << 3) + j;
    dst[f] = (col < Ks) ? f2bf(src[row * stride + col]) : (unsigned short)0;
  }
}

// fc1 + GRU (MFMA, weight-stationary): 32 rows/block, 8 waves (512 thr)
// blocks >= TRUNK_BLOCKS: remaining prep (transposes, wm/tm/wq swizzles, tmB)
__global__ __launch_bounds__(512, 4) void k_trunk(
    const float* __restrict__ inp, const float* __restrict__ hin,
    const unsigned short* __restrict__ fc1bf, const unsigned short* __restrict__ wihbf,
    const unsigned short* __restrict__ whhbf,
    const float* __restrict__ fc1_b, const float* __restrict__ bih, const float* __restrict__ bhh,
    float* __restrict__ hout, PrepP p, float* __restrict__ ws_f,
    unsigned short* __restrict__ wsu)
{
  __shared__ __align__(16) unsigned short in_b[32 * 168];
  __shared__ __align__(16) unsigned short x_b[32 * 72];
  __shared__ __align__(16) unsigned short h_b[32 * 72];
  int tid = threadIdx.x, w = tid >> 6, lane = tid & 63;
  int lo = lane & 15, hi = lane >> 4;

  if (blockIdx.x >= TRUNK_BLOCKS) {
    int eb = blockIdx.x - TRUNK_BLOCKS;
    if (eb < 24) {
      int b = eb >> 3, sl = eb & 7;
      const float* s = p.tsrc[b];
      float* d = ws_f + p.tOff[b];
      int O = p.tO[b], K = p.tK[b], n = O * K;
      for (int i = sl * 512 + tid; i < n; i += 8 * 512) {
        int o = i / K, k = i - o * K;
        d[k * O + o] = s[i];
      }
    } else if (eb < 104) {
      int q = eb - 24, m = q >> 4, sub = q & 15;   // m in 0..4 (wm1,wm2,wq,tm1,tm2)
      const float* src = p.ssrc[m];
      unsigned short* dst = wsu + p.sOff[m];
      int K = p.sK[m], Ks = p.sKs[m], stride = p.sSt[m], n = p.sO[m] * K, S = K >> 5;
      for (int f = sub * 512 + tid; f < n; f += 16 * 512) {
        int j = f & 7, l = (f >> 3) & 63, rest = f >> 9;
        int s = rest % S, c = rest / S;
        int row = c * 16 + (l & 15), col = s * 32 + ((l >> 4) << 3) + j;
        dst[f] = (col < Ks) ? f2bf(src[row * stride + col]) : (unsigned short)0;
      }
    } else {
      int i = (eb - 104) * 512 + tid;   // 4 blocks x 512 = 2048
      int j = i >> 8, o = i & 255;
      ws_f[TMB + i] = p.tm_b1[o] + p.tm_w1[o * 72 + 64 + j];
    }
    return;
  }

  int row0 = blockIdx.x * 32;
  int c = w & 3, rt = w >> 2;

  for (int i = tid; i < 1216; i += 512) {              // 32*152/4
    int e = i << 2;
    int r = e / 152, cc = e - r * 152;
    float4 v = LD4(inp + (size_t)(row0 + r) * 152 + cc);
    *(ushort4*)(in_b + r * 168 + cc) = f2bf4(v);
  }
  if (tid < 256) { int r = tid >> 3, cc = tid & 7; in_b[r * 168 + 152 + cc] = 0; }
  {
    int r = tid >> 4, cc = (tid & 15) << 2;            // 512 float4s, one per thread
    float4 v = LD4(hin + (size_t)(row0 + r) * 64 + cc);
    *(ushort4*)(h_b + r * 72 + cc) = f2bf4(v);
  }
  __syncthreads();

  bf16x8 wf1[5];
#pragma unroll
  for (int s = 0; s < 5; s++)
    wf1[s] = *(const bf16x8*)(fc1bf + (size_t)((c * 5 + s) * 64 + lane) * 8);
  f32x4 acc = {0, 0, 0, 0};
#pragma unroll
  for (int s = 0; s < 5; s++) {
    bf16x8 af = *(const bf16x8*)(in_b + (rt * 16 + lo) * 168 + s * 32 + hi * 8);
    acc = MFMA16(af, wf1[s], acc);
  }
  float fb = fc1_b[16 * c + lo];
#pragma unroll
  for (int r = 0; r < 4; r++)
    x_b[(rt * 16 + hi * 4 + r) * 72 + 16 * c + lo] = f2bf(fmaxf(acc[r] + fb, 0.f));
  __syncthreads();

  bf16x8 wfi[3][2], wfh[3][2];
#pragma unroll
  for (int t = 0; t < 3; t++)
#pragma unroll
    for (int s = 0; s < 2; s++) {
      int chunk = c + 4 * t;
      wfi[t][s] = *(const bf16x8*)(wihbf + (size_t)((chunk * 2 + s) * 64 + lane) * 8);
      wfh[t][s] = *(const bf16x8*)(whhbf + (size_t)((chunk * 2 + s) * 64 + lane) * 8);
    }
  f32x4 ai[3], ah[3];
#pragma unroll
  for (int t = 0; t < 3; t++) { ai[t] = {0,0,0,0}; ah[t] = {0,0,0,0}; }
#pragma unroll
  for (int s = 0; s < 2; s++) {
    bf16x8 ax  = *(const bf16x8*)(x_b + (rt * 16 + lo) * 72 + s * 32 + hi * 8);
    bf16x8 ahv = *(const bf16x8*)(h_b + (rt * 16 + lo) * 72 + s * 32 + hi * 8);
#pragma unroll
    for (int t = 0; t < 3; t++) {
      ai[t] = MFMA16(ax,  wfi[t][s], ai[t]);
      ah[t] = MFMA16(ahv, wfh[t][s], ah[t]);
    }
  }
  int col = 16 * c + lo;
  float b_ir = bih[col],       b_hr = bhh[col];
  float b_iz = bih[64 + col],  b_hz = bhh[64 + col];
  float b_in = bih[128 + col], b_hn = bhh[128 + col];
#pragma unroll
  for (int r = 0; r < 4; r++) {
    size_t grow = (size_t)(row0 + rt * 16 + hi * 4 + r);
    float rg = 1.f / (1.f + expf(-(ai[0][r] + b_ir + ah[0][r] + b_hr)));
    float zg = 1.f / (1.f + expf(-(ai[1][r] + b_iz + ah[1][r] + b_hz)));
    float ng = tanhf(fmaf(rg, ah[2][r] + b_hn, ai[2][r] + b_in));
    float h0 = hin[grow * 64 + col];
    hout[grow * 64 + col] = (1.f - zg) * ng + zg * h0;
  }
}

// teammate MLP + CE (MFMA, weight-stationary): 32 rows/block, 8 waves
__global__ __launch_bounds__(512, 4) void k_tm(
    const float* __restrict__ h,
    const unsigned short* __restrict__ w1b, const unsigned short* __restrict__ w2b,
    const float* __restrict__ tmB, const float* __restrict__ b2,
    const int* __restrict__ u,
    float* __restrict__ act, float* __restrict__ l1p)
{
  __shared__ __align__(16) unsigned short in_s[32 * 72];
  __shared__ __align__(16) unsigned short hid_s[32 * 264];
  __shared__ float red[512];
  int tid = threadIdx.x, w = tid >> 6, lane = tid & 63;
  int lo = lane & 15, hi = lane >> 4;
  int row0 = blockIdx.x * 32;
  {
    int r = tid >> 4, cc = (tid & 15) << 2;            // 512 float4s
    float4 v = LD4(h + (size_t)(row0 + r) * 64 + cc);
    *(ushort4*)(in_s + r * 72 + cc) = f2bf4(v);
  }
  bf16x8 wf1[2][2];
#pragma unroll
  for (int cc = 0; cc < 2; cc++)
#pragma unroll
    for (int s = 0; s < 2; s++)
      wf1[cc][s] = *(const bf16x8*)(w1b + (size_t)(((2 * w + cc) * 2 + s) * 64 + lane) * 8);
  __syncthreads();
  f32x4 acc[2][2];
#pragma unroll
  for (int rt = 0; rt < 2; rt++) { acc[rt][0] = {0,0,0,0}; acc[rt][1] = {0,0,0,0}; }
#pragma unroll
  for (int s = 0; s < 2; s++)
#pragma unroll
    for (int rt = 0; rt < 2; rt++) {
      bf16x8 af = *(const bf16x8*)(in_s + (rt * 16 + lo) * 72 + s * 32 + hi * 8);
      acc[rt][0] = MFMA16(af, wf1[0][s], acc[rt][0]);
      acc[rt][1] = MFMA16(af, wf1[1][s], acc[rt][1]);
    }
#pragma unroll
  for (int rt = 0; rt < 2; rt++)
#pragma unroll
    for (int r = 0; r < 4; r++) {
      int rowl = rt * 16 + hi * 4 + r, j = (hi * 4 + r) & 7;
      float v0 = acc[rt][0][r] + tmB[j * 256 + 32 * w + lo];
      float v1 = acc[rt][1][r] + tmB[j * 256 + 32 * w + 16 + lo];
      hid_s[rowl * 264 + 32 * w + lo]      = f2bf(fmaxf(v0, 0.f));
      hid_s[rowl * 264 + 32 * w + 16 + lo] = f2bf(fmaxf(v1, 0.f));
    }
  __syncthreads();
  float ces = 0.f;
  if (w < 2) {
    bf16x8 wf2[8];
#pragma unroll
    for (int s = 0; s < 8; s++)
      wf2[s] = *(const bf16x8*)(w2b + (size_t)(s * 64 + lane) * 8);
    f32x4 a2 = {0, 0, 0, 0};
#pragma unroll
    for (int s = 0; s < 8; s++) {
      bf16x8 af = *(const bf16x8*)(hid_s + (w * 16 + lo) * 264 + s * 32 + hi * 8);
      a2 = MFMA16(af, wf2[s], a2);
    }
    float b2c = b2[lo];
#pragma unroll
    for (int r = 0; r < 4; r++) {
      int rowl = w * 16 + hi * 4 + r;
      float v = a2[r] + b2c;
      act[(size_t)(row0 + rowl) * 16 + lo] = v;
      float m = v;
      m = fmaxf(m, __shfl_xor(m, 1));
      m = fmaxf(m, __shfl_xor(m, 2));
      m = fmaxf(m, __shfl_xor(m, 4));
      m = fmaxf(m, __shfl_xor(m, 8));
      float se = expf(v - m);
      se += __shfl_xor(se, 1);
      se += __shfl_xor(se, 2);
      se += __shfl_xor(se, 4);
      se += __shfl_xor(se, 8);
      int lbl = u[row0 + rowl];
      float vl = __shfl(v, (lane & 48) + lbl);
      if (lo == 0) ces += -(vl - m - logf(se));
    }
  }
  red[tid] = ces;
  __syncthreads();
  for (int st = 256; st > 0; st >>= 1) {
    if (tid < st) red[tid] += red[tid + st];
    __syncthreads();
  }
  if (tid == 0) l1p[blockIdx.x] = red[0];
}

// world model + MSE + query: 32 rows/block, 8 waves ; qry written bf16
__global__ __launch_bounds__(512, 4) void k_wm(
    const float* __restrict__ obs, const float* __restrict__ act,
    const unsigned short* __restrict__ w1b, const unsigned short* __restrict__ w2b,
    const unsigned short* __restrict__ wqb,
    const float* __restrict__ b1, const float* __restrict__ b2, const float* __restrict__ bq,
    const float* __restrict__ obsn,
    unsigned short* __restrict__ qryb, float* __restrict__ l2p)
{
  __shared__ __align__(16) unsigned short in_s[32 * 264];   // [obs | masked act] -> hid overlay
  __shared__ __align__(16) unsigned short q_in[32 * 264];   // [obs | onh]
  __shared__ __align__(16) unsigned short act_bs[4 * 128];
  __shared__ float red[512];
  int tid = threadIdx.x, w = tid >> 6, lane = tid & 63;
  int lo = lane & 15, hi = lane >> 4;
  int row0 = blockIdx.x * 32, e0 = row0 >> 3;
  if (tid < 128) {
    float4 v = LD4(act + (size_t)e0 * 128 + (tid << 2));
    *(ushort4*)(act_bs + (tid << 2)) = f2bf4(v);
  }
  for (int i = tid; i < 1024; i += 512) {               // 32*128/4
    int r = i >> 5, c = (i & 31) << 2;
    float4 v = LD4(obs + (size_t)(row0 + r) * 128 + c);
    ushort4 u4 = f2bf4(v);
    *(ushort4*)(in_s + r * 264 + c) = u4;
    *(ushort4*)(q_in + r * 264 + c) = u4;
  }
  bf16x8 wf1[2][8], wf2[8];
#pragma unroll
  for (int cc = 0; cc < 2; cc++)
#pragma unroll
    for (int s = 0; s < 8; s++)
      wf1[cc][s] = *(const bf16x8*)(w1b + (size_t)(((2 * w + cc) * 8 + s) * 64 + lane) * 8);
#pragma unroll
  for (int s = 0; s < 8; s++)
    wf2[s] = *(const bf16x8*)(w2b + (size_t)((w * 8 + s) * 64 + lane) * 8);
  __syncthreads();
  for (int i = tid; i < 1024; i += 512) {
    int r = i >> 5, c = (i & 31) << 2;
    int j = c >> 4, ii = r & 7;
    ushort4 v = (j == ii) ? make_ushort4(0, 0, 0, 0)
                          : *(const ushort4*)(act_bs + (r >> 3) * 128 + c);
    *(ushort4*)(in_s + r * 264 + 128 + c) = v;
  }
  __syncthreads();
  // layer1: wave w -> cols [32w, 32w+32)
  f32x4 acc[2][2];
#pragma unroll
  for (int rt = 0; rt < 2; rt++) { acc[rt][0] = {0,0,0,0}; acc[rt][1] = {0,0,0,0}; }
#pragma unroll
  for (int s = 0; s < 8; s++)
#pragma unroll
    for (int rt = 0; rt < 2; rt++) {
      bf16x8 af = *(const bf16x8*)(in_s + (rt * 16 + lo) * 264 + s * 32 + hi * 8);
      acc[rt][0] = MFMA16(af, wf1[0][s], acc[rt][0]);
      acc[rt][1] = MFMA16(af, wf1[1][s], acc[rt][1]);
    }
  float b1a = b1[32 * w + lo], b1b = b1[32 * w + 16 + lo];
  __syncthreads();
#pragma unroll
  for (int rt = 0; rt < 2; rt++)
#pragma unroll
    for (int r = 0; r < 4; r++) {
      int rowl = rt * 16 + hi * 4 + r;
      in_s[rowl * 264 + 32 * w + lo]      = f2bf(fmaxf(acc[rt][0][r] + b1a, 0.f));
      in_s[rowl * 264 + 32 * w + 16 + lo] = f2bf(fmaxf(acc[rt][1][r] + b1b, 0.f));
    }
  __syncthreads();
  // layer2: wave w -> cols [16w, 16w+16)
  f32x4 acc2[2];
  acc2[0] = {0, 0, 0, 0}; acc2[1] = {0, 0, 0, 0};
#pragma unroll
  for (int s = 0; s < 8; s++)
#pragma unroll
    for (int rt = 0; rt < 2; rt++) {
      bf16x8 af = *(const bf16x8*)(in_s + (rt * 16 + lo) * 264 + s * 32 + hi * 8);
      acc2[rt] = MFMA16(af, wf2[s], acc2[rt]);
    }
  int col = 16 * w + lo;
  float b2c = b2[col];
  float ms = 0.f;
#pragma unroll
  for (int rt = 0; rt < 2; rt++)
#pragma unroll
    for (int r = 0; r < 4; r++) {
      int rowl = rt * 16 + hi * 4 + r;
      float v = acc2[rt][r] + b2c;
      q_in[rowl * 264 + 128 + col] = f2bf(v);
      float d = v - obsn[(size_t)(row0 + rowl) * 128 + col];
      ms = fmaf(d, d, ms);
    }
  __syncthreads();
  // query: c = w&3, rt = w>>2 -> bf16 qry
  {
    int c = w & 3, rt = w >> 2;
    bf16x8 wf3[8];
#pragma unroll
    for (int s = 0; s < 8; s++)
      wf3[s] = *(const bf16x8*)(wqb + (size_t)((c * 8 + s) * 64 + lane) * 8);
    f32x4 aq = {0, 0, 0, 0};
#pragma unroll
    for (int s = 0; s < 8; s++) {
      bf16x8 af = *(const bf16x8*)(q_in + (rt * 16 + lo) * 264 + s * 32 + hi * 8);
      aq = MFMA16(af, wf3[s], aq);
    }
    float bqc = bq[16 * c + lo];
#pragma unroll
    for (int r = 0; r < 4; r++) {
      int row = row0 + rt * 16 + hi * 4 + r;
      qryb[(size_t)row * 64 + 16 * c + lo] = f2bf(aq[r] + bqc);
    }
  }
  red[tid] = ms;
  __syncthreads();
  for (int st = 256; st > 0; st >>= 1) {
    if (tid < st) red[tid] += red[tid + st];
    __syncthreads();
  }
  if (tid == 0) l2p[blockIdx.x] = red[0];
}

// fused key + value + attention (+ block0: loss finalize): 32 rows/block, 4 waves
__global__ __launch_bounds__(256, 4) void k_kva(
    const float* __restrict__ h, const float* __restrict__ act,
    const float* __restrict__ ws, const float* __restrict__ bk,
    const float* __restrict__ bv1, const float* __restrict__ bv2,
    const unsigned short* __restrict__ qryb, const float* __restrict__ l1p,
    const float* __restrict__ l2p, float* __restrict__ qout)
{
  __shared__ __align__(16) float in_s[32 * 80];
  __shared__ __align__(16) float hid_s[32 * 64];
  __shared__ __align__(16) float key_s[32 * 68];
  __shared__ float val_s[32 * 16];
  __shared__ float qs[4][64];
  __shared__ float red2[256];
  int tid = threadIdx.x, w = tid >> 6, lane = tid & 63;
  int row0 = blockIdx.x * 32;
  if (blockIdx.x == 0) {
    float s1 = l1p[tid] + l1p[tid + 256];
    float s2 = l2p[tid] + l2p[tid + 256];
    red2[tid] = s1;
    __syncthreads();
    for (int s = 128; s > 0; s >>= 1) {
      if (tid < s) red2[tid] += red2[tid + s];
      __syncthreads();
    }
    float S1 = red2[0];
    __syncthreads();
    red2[tid] = s2;
    __syncthreads();
    for (int s = 128; s > 0; s >>= 1) {
      if (tid < s) red2[tid] += red2[tid + s];
      __syncthreads();
    }
    if (tid == 0) {
      qout[DO_L1] = S1 * 7.f / 131072.f;
      qout[DO_L2] = red2[0] / 2097152.f;
    }
    __syncthreads();
  }
  for (int i = tid; i < 512; i += 256) {                 // 32*64/4 float4s
    int r = i >> 4, c = (i & 15) << 2;
    *(float4*)(in_s + r * 80 + c) = LD4(h + (size_t)(row0 + r) * 64 + c);
  }
  if (tid < 128) {                                       // 32*16/4
    int r = tid >> 2, c = (tid & 3) << 2;
    *(float4*)(in_s + r * 80 + 64 + c) = LD4(act + (size_t)(row0 + r) * 16 + c);
  }
  // prefetch this wave's 8 qry rows (bf16 -> f32)
  float qreg[8];
#pragma unroll
  for (int rr = 0; rr < 8; rr++)
    qreg[rr] = bf2f(qryb[(size_t)(row0 + w * 8 + rr) * 64 + lane]);
  __syncthreads();
  const float* w1T = ws + T_WV1;
  const float* w2T = ws + T_WV2;
  const float* wkT = ws + T_WK;
  float acc[8];
#pragma unroll
  for (int r = 0; r < 8; r++) acc[r] = bv1[lane];
  for (int k = 0; k < 80; k += 4) {
    float b[4];
#pragma unroll
    for (int j = 0; j < 4; j++) b[j] = w1T[(k + j) * 64 + lane];
#pragma unroll
    for (int r = 0; r < 8; r++) {
      float4 a = LD4(in_s + (w * 8 + r) * 80 + k);
      acc[r] = fmaf(a.x, b[0], fmaf(a.y, b[1], fmaf(a.z, b[2], fmaf(a.w, b[3], acc[r]))));
    }
  }
#pragma unroll
  for (int r = 0; r < 8; r++) hid_s[(w * 8 + r) * 64 + lane] = fmaxf(acc[r], 0.f);
  float ka[8];
#pragma unroll
  for (int r = 0; r < 8; r++) ka[r] = bk[lane];
  for (int k = 0; k < 16; k += 4) {
    float b[4];
#pragma unroll
    for (int j = 0; j < 4; j++) b[j] = wkT[(k + j) * 64 + lane];
#pragma unroll
    for (int r = 0; r < 8; r++) {
      float4 a = LD4(in_s + (w * 8 + r) * 80 + 64 + k);
      ka[r] = fmaf(a.x, b[0], fmaf(a.y, b[1], fmaf(a.z, b[2], fmaf(a.w, b[3], ka[r]))));
    }
  }
#pragma unroll
  for (int r = 0; r < 8; r++) key_s[(w * 8 + r) * 68 + lane] = ka[r];
  int col = lane & 15, kq = lane >> 4;
  float a2[8] = {0, 0, 0, 0, 0, 0, 0, 0};
  for (int kk = 0; kk < 16; kk += 4) {
    int k = kq * 16 + kk;
    float b[4];
#pragma unroll
    for (int j = 0; j < 4; j++) b[j] = w2T[(k + j) * 16 + col];
#pragma unroll
    for (int r = 0; r < 8; r++) {
      float4 a = LD4(hid_s + (w * 8 + r) * 64 + k);
      a2[r] = fmaf(a.x, b[0], fmaf(a.y, b[1], fmaf(a.z, b[2], fmaf(a.w, b[3], a2[r]))));
    }
  }
#pragma unroll
  for (int r = 0; r < 8; r++) {
    a2[r] += __shfl_xor(a2[r], 16);
    a2[r] += __shfl_xor(a2[r], 32);
  }
  if (lane < 16) {
#pragma unroll
    for (int r = 0; r < 8; r++) val_s[(w * 8 + r) * 16 + col] = a2[r] + bv2[col];
  }
  int j = lane >> 3, p = lane & 7;
  for (int rr = 0; rr < 8; rr++) {
    int b = row0 + w * 8 + rr;
    qs[w][lane] = qreg[rr];
    const float* krow = key_s + (w * 8 + j) * 68;
    float s = 0.f;
#pragma unroll
    for (int t = 0; t < 8; t++) {
      int d = p * 8 + t;
      s = fmaf(qs[w][d], krow[d], s);
    }
    s += __shfl_xor(s, 1);
    s += __shfl_xor(s, 2);
    s += __shfl_xor(s, 4);
    float score = (j == rr) ? -1e9f : s * 0.125f;
    float sc[8];
    float m = -1e30f;
#pragma unroll
    for (int jj = 0; jj < 8; jj++) {
      sc[jj] = __shfl(score, jj * 8);
      m = fmaxf(m, sc[jj]);
    }
    float ssum = 0.f;
#pragma unroll
    for (int jj = 0; jj < 8; jj++) { sc[jj] = expf(sc[jj] - m); ssum += sc[jj]; }
    float inv = 1.f / ssum;
    int c = lane & 15, g = lane >> 4;
    const float* vb = val_s + w * 8 * 16;
    float outv = sc[g] * inv * vb[g * 16 + c] + sc[g + 4] * inv * vb[(g + 4) * 16 + c];
    outv += __shfl_xor(outv, 16);
    outv += __shfl_xor(outv, 32);
    if (lane < 16) qout[(size_t)b * 16 + lane] = outv;
  }
}

extern "C" void kernel_launch(void* const* d_in, const int* in_sizes, int n_in,
                              void* d_out, int out_size, void* d_ws, size_t ws_size,
                              hipStream_t stream) {
  const float* inputs   = (const float*)d_in[0];
  const float* hidden   = (const float*)d_in[1];
  const float* obs      = (const float*)d_in[2];
  const float* obs_next = (const float*)d_in[3];
  const int*   u        = (const int*)d_in[4];
  const float* fc1_w = (const float*)d_in[5];   const float* fc1_b = (const float*)d_in[6];
  const float* wih   = (const float*)d_in[7];   const float* bih   = (const float*)d_in[8];
  const float* whh   = (const float*)d_in[9];   const float* bhh   = (const float*)d_in[10];
  const float* tm_w1 = (const float*)d_in[11];  const float* tm_b1 = (const float*)d_in[12];
  const float* tm_w2 = (const float*)d_in[13];  const float* tm_b2 = (const float*)d_in[14];
  const float* wm_w1 = (const float*)d_in[15];  const float* wm_b1 = (const float*)d_in[16];
  const float* wm_w2 = (const float*)d_in[17];  const float* wm_b2 = (const float*)d_in[18];
  const float* wq_w  = (const float*)d_in[19];  const float* wq_b  = (const float*)d_in[20];
  const float* wk_w  = (const float*)d_in[21];  const float* wk_b  = (const float*)d_in[22];
  const float* wv1_w = (const float*)d_in[23];  const float* wv1_b = (const float*)d_in[24];
  const float* wv2_w = (const float*)d_in[25];  const float* wv2_b = (const float*)d_in[26];

  float* ws   = (float*)d_ws;
  unsigned short* wsu = (unsigned short*)d_ws;
  float* out  = (float*)d_out;
  float* hbuf = out + DO_H;

  PrepP p;
  const float* tsr[3] = {wk_w, wv1_w, wv2_w};
  int tO[3]  = {64, 64, 16};
  int tK[3]  = {16, 80, 64};
  int tOf[3] = {T_WK, T_WV1, T_WV2};
  for (int i = 0; i < 3; i++) { p.tsrc[i] = tsr[i]; p.tO[i] = tO[i]; p.tK[i] = tK[i]; p.tOff[i] = tOf[i]; }
  const float* ssr[8] = {wm_w1, wm_w2, wq_w, tm_w1, tm_w2, fc1_w, wih, whh};
  int sO[8]  = {256, 128, 64, 256, 16, 64, 192, 192};
  int sK[8]  = {256, 256, 256, 64, 256, 160, 64, 64};
  int sKs[8] = {256, 256, 256, 64, 256, 152, 64, 64};
  int sSt[8] = {256, 256, 256, 72, 256, 152, 64, 64};
  int sOf[8] = {B_WM1*2, B_WM2*2, B_WQ*2, B_TM1*2, B_TM2*2, B_FC1*2, B_WIH*2, B_WHH*2};
  for (int i = 0; i < 8; i++) {
    p.ssrc[i] = ssr[i]; p.sO[i] = sO[i]; p.sK[i] = sK[i];
    p.sKs[i] = sKs[i]; p.sSt[i] = sSt[i]; p.sOff[i] = sOf[i];
  }
  p.tm_w1 = tm_w1; p.tm_b1 = tm_b1;

  k_prep<<<48, 256, 0, stream>>>(p, ws, wsu);
  k_trunk<<<TRUNK_BLOCKS + TRUNK_EXTRA, 512, 0, stream>>>(inputs, hidden,
      wsu + B_FC1*2, wsu + B_WIH*2, wsu + B_WHH*2, fc1_b, bih, bhh, hbuf, p, ws, wsu);
  k_tm<<<ROWS / 32, 512, 0, stream>>>(hbuf, wsu + B_TM1*2, wsu + B_TM2*2,
      ws + TMB, tm_b2, u, ws + O_ACT, ws + O_L1P);
  k_wm<<<ROWS / 32, 512, 0, stream>>>(obs, ws + O_ACT,
      wsu + B_WM1*2, wsu + B_WM2*2, wsu + B_WQ*2, wm_b1, wm_b2, wq_b, obs_next,
      wsu + O_QRY * 2, ws + O_L2P);
  k_kva<<<ROWS / 32, 256, 0, stream>>>(hbuf, ws + O_ACT, ws, wk_b, wv1_b, wv2_b,
      wsu + O_QRY * 2, ws + O_L1P, ws + O_L2P, out);
}

// Round 14
// 45.623 us; speedup vs baseline: 1.7191x; 1.0791x over previous
//
#include <hip/hip_runtime.h>
#include <math.h>

#define E_NUM 2048
#define A_N   8
#define ROWS  (E_NUM*A_N)   // 16384
#define TRUNK_BLOCKS 512
#define TRUNK_EXTRA  108    // 24 transpose + 80 swizzle + 4 tmB

typedef __attribute__((ext_vector_type(8))) short bf16x8;
typedef __attribute__((ext_vector_type(4))) float f32x4;

__device__ __forceinline__ unsigned short f2bf(float x) {
  unsigned int u = __float_as_uint(x);
  return (unsigned short)((u + 0x7FFFu + ((u >> 16) & 1u)) >> 16);
}
__device__ __forceinline__ ushort4 f2bf4(float4 v) {
  return make_ushort4(f2bf(v.x), f2bf(v.y), f2bf(v.z), f2bf(v.w));
}
__device__ __forceinline__ float bf2f(unsigned short u) {
  return __uint_as_float(((unsigned int)u) << 16);
}
#define MFMA16(a,b,c) __builtin_amdgcn_mfma_f32_16x16x32_bf16(a,b,c,0,0,0)

// ---- ws layout (float offsets) ----
#define T_WK   0         // 16*64 f32 transposed
#define T_WV1  1024      // 80*64
#define T_WV2  6144      // 64*16
#define TMB    7168      // 8*256 f32
#define B_WM1  9216      // 256x256 bf16 frag-major (32768 fl)
#define B_WM2  41984     // 128x256 (16384 fl)
#define B_WQ   58368     // 64x256 (8192 fl)
#define B_TM1  66560     // 256x64 (8192 fl)
#define B_TM2  74752     // 16x256 (2048 fl)
#define B_FC1  76800     // 64x160 (5120 fl)
#define B_WIH  81920     // 192x64 (6144 fl)
#define B_WHH  88064     // 192x64 (6144 fl)
#define O_ACT  94208     // 16384*16 f32
#define O_QRY  356352    // 16384*64 bf16
#define O_L1P  1404928   // 512
#define O_L2P  1405440   // 512

// d_out: q_reflect [0,262144) ; h ; loss1 ; loss2
#define DO_H   262144
#define DO_L1  1310720
#define DO_L2  1310721

#define LD4(p) (*(const float4*)(p))

struct PrepP {
  const float* tsrc[3]; int tO[3], tK[3], tOff[3];
  const float* ssrc[8]; int sO[8], sK[8], sKs[8], sSt[8], sOff[8]; // sOff in ushort units
  const float* tm_w1; const float* tm_b1;
};

// 48 blocks: bf16 frag swizzle of fc1/wih/whh only (what k_trunk needs)
__global__ __launch_bounds__(256) void k_prep(PrepP p, float* __restrict__ ws,
                                              unsigned short* __restrict__ wsu) {
  int bid = blockIdx.x;
  int m = 5 + (bid >> 4), sub = bid & 15;
  const float* src = p.ssrc[m];
  unsigned short* dst = wsu + p.sOff[m];
  int K = p.sK[m], Ks = p.sKs[m], stride = p.sSt[m], n = p.sO[m] * K, S = K >> 5;
  for (int f = sub * 256 + threadIdx.x; f < n; f += 16 * 256) {
    int j = f & 7, l = (f >> 3) & 63, rest = f >> 9;
    int s = rest % S, c = rest / S;
    int row = c * 16 + (l & 15), col = s * 32 + ((l >> 4) << 3) + j;
    dst[f] = (col < Ks) ? f2bf(src[row * stride + col]) : (unsigned short)0;
  }
}

// fc1 + GRU (MFMA, weight-stationary): 32 rows/block, 8 waves (512 thr)
// blocks >= TRUNK_BLOCKS: remaining prep (transposes, wm/tm/wq swizzles, tmB)
__global__ __launch_bounds__(512, 4) void k_trunk(
    const float* __restrict__ inp, const float* __restrict__ hin,
    const unsigned short* __restrict__ fc1bf, const unsigned short* __restrict__ wihbf,
    const unsigned short* __restrict__ whhbf,
    const float* __restrict__ fc1_b, const float* __restrict__ bih, const float* __restrict__ bhh,
    float* __restrict__ hout, PrepP p, float* __restrict__ ws_f,
    unsigned short* __restrict__ wsu)
{
  __shared__ __align__(16) unsigned short in_b[32 * 168];
  __shared__ __align__(16) unsigned short x_b[32 * 72];
  __shared__ __align__(16) unsigned short h_b[32 * 72];
  int tid = threadIdx.x, w = tid >> 6, lane = tid & 63;
  int lo = lane & 15, hi = lane >> 4;

  if (blockIdx.x >= TRUNK_BLOCKS) {
    int eb = blockIdx.x - TRUNK_BLOCKS;
    if (eb < 24) {
      int b = eb >> 3, sl = eb & 7;
      const float* s = p.tsrc[b];
      float* d = ws_f + p.tOff[b];
      int O = p.tO[b], K = p.tK[b], n = O * K;
      for (int i = sl * 512 + tid; i < n; i += 8 * 512) {
        int o = i / K, k = i - o * K;
        d[k * O + o] = s[i];
      }
    } else if (eb < 104) {
      int q = eb - 24, m = q >> 4, sub = q & 15;   // m in 0..4 (wm1,wm2,wq,tm1,tm2)
      const float* src = p.ssrc[m];
      unsigned short* dst = wsu + p.sOff[m];
      int K = p.sK[m], Ks = p.sKs[m], stride = p.sSt[m], n = p.sO[m] * K, S = K >> 5;
      for (int f = sub * 512 + tid; f < n; f += 16 * 512) {
        int j = f & 7, l = (f >> 3) & 63, rest = f >> 9;
        int s = rest % S, c = rest / S;
        int row = c * 16 + (l & 15), col = s * 32 + ((l >> 4) << 3) + j;
        dst[f] = (col < Ks) ? f2bf(src[row * stride + col]) : (unsigned short)0;
      }
    } else {
      int i = (eb - 104) * 512 + tid;   // 4 blocks x 512 = 2048
      int j = i >> 8, o = i & 255;
      ws_f[TMB + i] = p.tm_b1[o] + p.tm_w1[o * 72 + 64 + j];
    }
    return;
  }

  int row0 = blockIdx.x * 32;
  int c = w & 3, rt = w >> 2;

  for (int i = tid; i < 1216; i += 512) {              // 32*152/4
    int e = i << 2;
    int r = e / 152, cc = e - r * 152;
    float4 v = LD4(inp + (size_t)(row0 + r) * 152 + cc);
    *(ushort4*)(in_b + r * 168 + cc) = f2bf4(v);
  }
  if (tid < 256) { int r = tid >> 3, cc = tid & 7; in_b[r * 168 + 152 + cc] = 0; }
  {
    int r = tid >> 4, cc = (tid & 15) << 2;            // 512 float4s, one per thread
    float4 v = LD4(hin + (size_t)(row0 + r) * 64 + cc);
    *(ushort4*)(h_b + r * 72 + cc) = f2bf4(v);
  }
  __syncthreads();

  bf16x8 wf1[5];
#pragma unroll
  for (int s = 0; s < 5; s++)
    wf1[s] = *(const bf16x8*)(fc1bf + (size_t)((c * 5 + s) * 64 + lane) * 8);
  f32x4 acc = {0, 0, 0, 0};
#pragma unroll
  for (int s = 0; s < 5; s++) {
    bf16x8 af = *(const bf16x8*)(in_b + (rt * 16 + lo) * 168 + s * 32 + hi * 8);
    acc = MFMA16(af, wf1[s], acc);
  }
  float fb = fc1_b[16 * c + lo];
#pragma unroll
  for (int r = 0; r < 4; r++)
    x_b[(rt * 16 + hi * 4 + r) * 72 + 16 * c + lo] = f2bf(fmaxf(acc[r] + fb, 0.f));
  __syncthreads();

  bf16x8 wfi[3][2], wfh[3][2];
#pragma unroll
  for (int t = 0; t < 3; t++)
#pragma unroll
    for (int s = 0; s < 2; s++) {
      int chunk = c + 4 * t;
      wfi[t][s] = *(const bf16x8*)(wihbf + (size_t)((chunk * 2 + s) * 64 + lane) * 8);
      wfh[t][s] = *(const bf16x8*)(whhbf + (size_t)((chunk * 2 + s) * 64 + lane) * 8);
    }
  f32x4 ai[3], ah[3];
#pragma unroll
  for (int t = 0; t < 3; t++) { ai[t] = {0,0,0,0}; ah[t] = {0,0,0,0}; }
#pragma unroll
  for (int s = 0; s < 2; s++) {
    bf16x8 ax  = *(const bf16x8*)(x_b + (rt * 16 + lo) * 72 + s * 32 + hi * 8);
    bf16x8 ahv = *(const bf16x8*)(h_b + (rt * 16 + lo) * 72 + s * 32 + hi * 8);
#pragma unroll
    for (int t = 0; t < 3; t++) {
      ai[t] = MFMA16(ax,  wfi[t][s], ai[t]);
      ah[t] = MFMA16(ahv, wfh[t][s], ah[t]);
    }
  }
  int col = 16 * c + lo;
  float b_ir = bih[col],       b_hr = bhh[col];
  float b_iz = bih[64 + col],  b_hz = bhh[64 + col];
  float b_in = bih[128 + col], b_hn = bhh[128 + col];
#pragma unroll
  for (int r = 0; r < 4; r++) {
    size_t grow = (size_t)(row0 + rt * 16 + hi * 4 + r);
    float rg = 1.f / (1.f + expf(-(ai[0][r] + b_ir + ah[0][r] + b_hr)));
    float zg = 1.f / (1.f + expf(-(ai[1][r] + b_iz + ah[1][r] + b_hz)));
    float ng = tanhf(fmaf(rg, ah[2][r] + b_hn, ai[2][r] + b_in));
    float h0 = hin[grow * 64 + col];
    hout[grow * 64 + col] = (1.f - zg) * ng + zg * h0;
  }
}

// teammate MLP + CE (MFMA, weight-stationary): 32 rows/block, 8 waves
__global__ __launch_bounds__(512, 4) void k_tm(
    const float* __restrict__ h,
    const unsigned short* __restrict__ w1b, const unsigned short* __restrict__ w2b,
    const float* __restrict__ tmB, const float* __restrict__ b2,
    const int* __restrict__ u,
    float* __restrict__ act, float* __restrict__ l1p)
{
  __shared__ __align__(16) unsigned short in_s[32 * 72];
  __shared__ __align__(16) unsigned short hid_s[32 * 264];
  __shared__ float red[512];
  int tid = threadIdx.x, w = tid >> 6, lane = tid & 63;
  int lo = lane & 15, hi = lane >> 4;
  int row0 = blockIdx.x * 32;
  {
    int r = tid >> 4, cc = (tid & 15) << 2;            // 512 float4s
    float4 v = LD4(h + (size_t)(row0 + r) * 64 + cc);
    *(ushort4*)(in_s + r * 72 + cc) = f2bf4(v);
  }
  bf16x8 wf1[2][2];
#pragma unroll
  for (int cc = 0; cc < 2; cc++)
#pragma unroll
    for (int s = 0; s < 2; s++)
      wf1[cc][s] = *(const bf16x8*)(w1b + (size_t)(((2 * w + cc) * 2 + s) * 64 + lane) * 8);
  __syncthreads();
  f32x4 acc[2][2];
#pragma unroll
  for (int rt = 0; rt < 2; rt++) { acc[rt][0] = {0,0,0,0}; acc[rt][1] = {0,0,0,0}; }
#pragma unroll
  for (int s = 0; s < 2; s++)
#pragma unroll
    for (int rt = 0; rt < 2; rt++) {
      bf16x8 af = *(const bf16x8*)(in_s + (rt * 16 + lo) * 72 + s * 32 + hi * 8);
      acc[rt][0] = MFMA16(af, wf1[0][s], acc[rt][0]);
      acc[rt][1] = MFMA16(af, wf1[1][s], acc[rt][1]);
    }
#pragma unroll
  for (int rt = 0; rt < 2; rt++)
#pragma unroll
    for (int r = 0; r < 4; r++) {
      int rowl = rt * 16 + hi * 4 + r, j = (hi * 4 + r) & 7;
      float v0 = acc[rt][0][r] + tmB[j * 256 + 32 * w + lo];
      float v1 = acc[rt][1][r] + tmB[j * 256 + 32 * w + 16 + lo];
      hid_s[rowl * 264 + 32 * w + lo]      = f2bf(fmaxf(v0, 0.f));
      hid_s[rowl * 264 + 32 * w + 16 + lo] = f2bf(fmaxf(v1, 0.f));
    }
  __syncthreads();
  float ces = 0.f;
  if (w < 2) {
    bf16x8 wf2[8];
#pragma unroll
    for (int s = 0; s < 8; s++)
      wf2[s] = *(const bf16x8*)(w2b + (size_t)(s * 64 + lane) * 8);
    f32x4 a2 = {0, 0, 0, 0};
#pragma unroll
    for (int s = 0; s < 8; s++) {
      bf16x8 af = *(const bf16x8*)(hid_s + (w * 16 + lo) * 264 + s * 32 + hi * 8);
      a2 = MFMA16(af, wf2[s], a2);
    }
    float b2c = b2[lo];
#pragma unroll
    for (int r = 0; r < 4; r++) {
      int rowl = w * 16 + hi * 4 + r;
      float v = a2[r] + b2c;
      act[(size_t)(row0 + rowl) * 16 + lo] = v;
      float m = v;
      m = fmaxf(m, __shfl_xor(m, 1));
      m = fmaxf(m, __shfl_xor(m, 2));
      m = fmaxf(m, __shfl_xor(m, 4));
      m = fmaxf(m, __shfl_xor(m, 8));
      float se = expf(v - m);
      se += __shfl_xor(se, 1);
      se += __shfl_xor(se, 2);
      se += __shfl_xor(se, 4);
      se += __shfl_xor(se, 8);
      int lbl = u[row0 + rowl];
      float vl = __shfl(v, (lane & 48) + lbl);
      if (lo == 0) ces += -(vl - m - logf(se));
    }
  }
  red[tid] = ces;
  __syncthreads();
  for (int st = 256; st > 0; st >>= 1) {
    if (tid < st) red[tid] += red[tid + st];
    __syncthreads();
  }
  if (tid == 0) l1p[blockIdx.x] = red[0];
}

// world model + MSE + query: 32 rows/block, 8 waves ; qry written bf16
__global__ __launch_bounds__(512, 4) void k_wm(
    const float* __restrict__ obs, const float* __restrict__ act,
    const unsigned short* __restrict__ w1b, const unsigned short* __restrict__ w2b,
    const unsigned short* __restrict__ wqb,
    const float* __restrict__ b1, const float* __restrict__ b2, const float* __restrict__ bq,
    const float* __restrict__ obsn,
    unsigned short* __restrict__ qryb, float* __restrict__ l2p)
{
  __shared__ __align__(16) unsigned short in_s[32 * 264];   // [obs | masked act] -> hid overlay
  __shared__ __align__(16) unsigned short q_in[32 * 264];   // [obs | onh]
  __shared__ __align__(16) unsigned short act_bs[4 * 128];
  __shared__ float red[512];
  int tid = threadIdx.x, w = tid >> 6, lane = tid & 63;
  int lo = lane & 15, hi = lane >> 4;
  int row0 = blockIdx.x * 32, e0 = row0 >> 3;
  if (tid < 128) {
    float4 v = LD4(act + (size_t)e0 * 128 + (tid << 2));
    *(ushort4*)(act_bs + (tid << 2)) = f2bf4(v);
  }
  for (int i = tid; i < 1024; i += 512) {               // 32*128/4
    int r = i >> 5, c = (i & 31) << 2;
    float4 v = LD4(obs + (size_t)(row0 + r) * 128 + c);
    ushort4 u4 = f2bf4(v);
    *(ushort4*)(in_s + r * 264 + c) = u4;
    *(ushort4*)(q_in + r * 264 + c) = u4;
  }
  bf16x8 wf1[2][8], wf2[8];
#pragma unroll
  for (int cc = 0; cc < 2; cc++)
#pragma unroll
    for (int s = 0; s < 8; s++)
      wf1[cc][s] = *(const bf16x8*)(w1b + (size_t)(((2 * w + cc) * 8 + s) * 64 + lane) * 8);
#pragma unroll
  for (int s = 0; s < 8; s++)
    wf2[s] = *(const bf16x8*)(w2b + (size_t)((w * 8 + s) * 64 + lane) * 8);
  __syncthreads();
  for (int i = tid; i < 1024; i += 512) {
    int r = i >> 5, c = (i & 31) << 2;
    int j = c >> 4, ii = r & 7;
    ushort4 v = (j == ii) ? make_ushort4(0, 0, 0, 0)
                          : *(const ushort4*)(act_bs + (r >> 3) * 128 + c);
    *(ushort4*)(in_s + r * 264 + 128 + c) = v;
  }
  __syncthreads();
  // layer1: wave w -> cols [32w, 32w+32)
  f32x4 acc[2][2];
#pragma unroll
  for (int rt = 0; rt < 2; rt++) { acc[rt][0] = {0,0,0,0}; acc[rt][1] = {0,0,0,0}; }
#pragma unroll
  for (int s = 0; s < 8; s++)
#pragma unroll
    for (int rt = 0; rt < 2; rt++) {
      bf16x8 af = *(const bf16x8*)(in_s + (rt * 16 + lo) * 264 + s * 32 + hi * 8);
      acc[rt][0] = MFMA16(af, wf1[0][s], acc[rt][0]);
      acc[rt][1] = MFMA16(af, wf1[1][s], acc[rt][1]);
    }
  float b1a = b1[32 * w + lo], b1b = b1[32 * w + 16 + lo];
  __syncthreads();
#pragma unroll
  for (int rt = 0; rt < 2; rt++)
#pragma unroll
    for (int r = 0; r < 4; r++) {
      int rowl = rt * 16 + hi * 4 + r;
      in_s[rowl * 264 + 32 * w + lo]      = f2bf(fmaxf(acc[rt][0][r] + b1a, 0.f));
      in_s[rowl * 264 + 32 * w + 16 + lo] = f2bf(fmaxf(acc[rt][1][r] + b1b, 0.f));
    }
  __syncthreads();
  // layer2: wave w -> cols [16w, 16w+16)
  f32x4 acc2[2];
  acc2[0] = {0, 0, 0, 0}; acc2[1] = {0, 0, 0, 0};
#pragma unroll
  for (int s = 0; s < 8; s++)
#pragma unroll
    for (int rt = 0; rt < 2; rt++) {
      bf16x8 af = *(const bf16x8*)(in_s + (rt * 16 + lo) * 264 + s * 32 + hi * 8);
      acc2[rt] = MFMA16(af, wf2[s], acc2[rt]);
    }
  int col = 16 * w + lo;
  float b2c = b2[col];
  float ms = 0.f;
#pragma unroll
  for (int rt = 0; rt < 2; rt++)
#pragma unroll
    for (int r = 0; r < 4; r++) {
      int rowl = rt * 16 + hi * 4 + r;
      float v = acc2[rt][r] + b2c;
      q_in[rowl * 264 + 128 + col] = f2bf(v);
      float d = v - obsn[(size_t)(row0 + rowl) * 128 + col];
      ms = fmaf(d, d, ms);
    }
  __syncthreads();
  // query: c = w&3, rt = w>>2 -> bf16 qry
  {
    int c = w & 3, rt = w >> 2;
    bf16x8 wf3[8];
#pragma unroll
    for (int s = 0; s < 8; s++)
      wf3[s] = *(const bf16x8*)(wqb + (size_t)((c * 8 + s) * 64 + lane) * 8);
    f32x4 aq = {0, 0, 0, 0};
#pragma unroll
    for (int s = 0; s < 8; s++) {
      bf16x8 af = *(const bf16x8*)(q_in + (rt * 16 + lo) * 264 + s * 32 + hi * 8);
      aq = MFMA16(af, wf3[s], aq);
    }
    float bqc = bq[16 * c + lo];
#pragma unroll
    for (int r = 0; r < 4; r++) {
      int row = row0 + rt * 16 + hi * 4 + r;
      qryb[(size_t)row * 64 + 16 * c + lo] = f2bf(aq[r] + bqc);
    }
  }
  red[tid] = ms;
  __syncthreads();
  for (int st = 256; st > 0; st >>= 1) {
    if (tid < st) red[tid] += red[tid + st];
    __syncthreads();
  }
  if (tid == 0) l2p[blockIdx.x] = red[0];
}

// fused key + value + attention (+ block0: loss finalize): 32 rows/block, 8 waves x 4 rows
__global__ __launch_bounds__(512, 4) void k_kva(
    const float* __restrict__ h, const float* __restrict__ act,
    const float* __restrict__ ws, const float* __restrict__ bk,
    const float* __restrict__ bv1, const float* __restrict__ bv2,
    const unsigned short* __restrict__ qryb, const float* __restrict__ l1p,
    const float* __restrict__ l2p, float* __restrict__ qout)
{
  __shared__ __align__(16) float in_s[32 * 80];
  __shared__ __align__(16) float hid_s[32 * 64];
  __shared__ __align__(16) float key_s[32 * 68];
  __shared__ float val_s[32 * 16];
  __shared__ float qs[8][64];
  __shared__ float red2[512];
  int tid = threadIdx.x, w = tid >> 6, lane = tid & 63;
  int row0 = blockIdx.x * 32;
  if (blockIdx.x == 0) {
    red2[tid] = l1p[tid];
    __syncthreads();
    for (int s = 256; s > 0; s >>= 1) {
      if (tid < s) red2[tid] += red2[tid + s];
      __syncthreads();
    }
    float S1 = red2[0];
    __syncthreads();
    red2[tid] = l2p[tid];
    __syncthreads();
    for (int s = 256; s > 0; s >>= 1) {
      if (tid < s) red2[tid] += red2[tid + s];
      __syncthreads();
    }
    if (tid == 0) {
      qout[DO_L1] = S1 * 7.f / 131072.f;
      qout[DO_L2] = red2[0] / 2097152.f;
    }
    __syncthreads();
  }
  {
    int r = tid >> 4, c = (tid & 15) << 2;               // 512 float4s (32*64/4)
    *(float4*)(in_s + r * 80 + c) = LD4(h + (size_t)(row0 + r) * 64 + c);
  }
  if (tid < 128) {                                       // 32*16/4
    int r = tid >> 2, c = (tid & 3) << 2;
    *(float4*)(in_s + r * 80 + 64 + c) = LD4(act + (size_t)(row0 + r) * 16 + c);
  }
  // prefetch this wave's 4 qry rows (bf16 -> f32)
  float qreg[4];
#pragma unroll
  for (int rr = 0; rr < 4; rr++)
    qreg[rr] = bf2f(qryb[(size_t)(row0 + w * 4 + rr) * 64 + lane]);
  __syncthreads();
  const float* w1T = ws + T_WV1;
  const float* w2T = ws + T_WV2;
  const float* wkT = ws + T_WK;
  // value layer1 + key: wave rows w*4..w*4+3
  float acc[4], ka[4];
#pragma unroll
  for (int r = 0; r < 4; r++) { acc[r] = bv1[lane]; ka[r] = bk[lane]; }
  for (int k = 0; k < 80; k += 4) {
    float b[4];
#pragma unroll
    for (int j = 0; j < 4; j++) b[j] = w1T[(k + j) * 64 + lane];
#pragma unroll
    for (int r = 0; r < 4; r++) {
      float4 a = LD4(in_s + (w * 4 + r) * 80 + k);
      acc[r] = fmaf(a.x, b[0], fmaf(a.y, b[1], fmaf(a.z, b[2], fmaf(a.w, b[3], acc[r]))));
    }
  }
  for (int k = 0; k < 16; k += 4) {
    float b[4];
#pragma unroll
    for (int j = 0; j < 4; j++) b[j] = wkT[(k + j) * 64 + lane];
#pragma unroll
    for (int r = 0; r < 4; r++) {
      float4 a = LD4(in_s + (w * 4 + r) * 80 + 64 + k);
      ka[r] = fmaf(a.x, b[0], fmaf(a.y, b[1], fmaf(a.z, b[2], fmaf(a.w, b[3], ka[r]))));
    }
  }
#pragma unroll
  for (int r = 0; r < 4; r++) {
    hid_s[(w * 4 + r) * 64 + lane] = fmaxf(acc[r], 0.f);
    key_s[(w * 4 + r) * 68 + lane] = ka[r];
  }
  // value layer2 (wave-local hid rows)
  {
    int col = lane & 15, kq = lane >> 4;
    float a2[4] = {0, 0, 0, 0};
    for (int kk = 0; kk < 16; kk += 4) {
      int k = kq * 16 + kk;
      float b[4];
#pragma unroll
      for (int j = 0; j < 4; j++) b[j] = w2T[(k + j) * 16 + col];
#pragma unroll
      for (int r = 0; r < 4; r++) {
        float4 a = LD4(hid_s + (w * 4 + r) * 64 + k);
        a2[r] = fmaf(a.x, b[0], fmaf(a.y, b[1], fmaf(a.z, b[2], fmaf(a.w, b[3], a2[r]))));
      }
    }
#pragma unroll
    for (int r = 0; r < 4; r++) {
      a2[r] += __shfl_xor(a2[r], 16);
      a2[r] += __shfl_xor(a2[r], 32);
    }
    if (lane < 16)
#pragma unroll
      for (int r = 0; r < 4; r++) val_s[(w * 4 + r) * 16 + col] = a2[r] + bv2[col];
  }
  __syncthreads();   // key_s/val_s complete for all episodes in block
  // attention: wave w -> local rows w*4..w*4+3 (episode ep = w>>1)
  {
    int ep = w >> 1;
    int j = lane >> 3, p = lane & 7;
    for (int q2 = 0; q2 < 4; q2++) {
      int bl = w * 4 + q2;           // local row
      int rr = bl & 7;               // agent index within episode
      qs[w][lane] = qreg[q2];
      const float* krow = key_s + (ep * 8 + j) * 68;
      float s = 0.f;
#pragma unroll
      for (int t = 0; t < 8; t++) {
        int d = p * 8 + t;
        s = fmaf(qs[w][d], krow[d], s);
      }
      s += __shfl_xor(s, 1);
      s += __shfl_xor(s, 2);
      s += __shfl_xor(s, 4);
      float score = (j == rr) ? -1e9f : s * 0.125f;
      float sc[8];
      float m = -1e30f;
#pragma unroll
      for (int jj = 0; jj < 8; jj++) {
        sc[jj] = __shfl(score, jj * 8);
        m = fmaxf(m, sc[jj]);
      }
      float ssum = 0.f;
#pragma unroll
      for (int jj = 0; jj < 8; jj++) { sc[jj] = expf(sc[jj] - m); ssum += sc[jj]; }
      float inv = 1.f / ssum;
      int c = lane & 15, g = lane >> 4;
      const float* vb = val_s + ep * 128;
      float outv = sc[g] * inv * vb[g * 16 + c] + sc[g + 4] * inv * vb[(g + 4) * 16 + c];
      outv += __shfl_xor(outv, 16);
      outv += __shfl_xor(outv, 32);
      if (lane < 16) qout[(size_t)(row0 + bl) * 16 + lane] = outv;
    }
  }
}

extern "C" void kernel_launch(void* const* d_in, const int* in_sizes, int n_in,
                              void* d_out, int out_size, void* d_ws, size_t ws_size,
                              hipStream_t stream) {
  const float* inputs   = (const float*)d_in[0];
  const float* hidden   = (const float*)d_in[1];
  const float* obs      = (const float*)d_in[2];
  const float* obs_next = (const float*)d_in[3];
  const int*   u        = (const int*)d_in[4];
  const float* fc1_w = (const float*)d_in[5];   const float* fc1_b = (const float*)d_in[6];
  const float* wih   = (const float*)d_in[7];   const float* bih   = (const float*)d_in[8];
  const float* whh   = (const float*)d_in[9];   const float* bhh   = (const float*)d_in[10];
  const float* tm_w1 = (const float*)d_in[11];  const float* tm_b1 = (const float*)d_in[12];
  const float* tm_w2 = (const float*)d_in[13];  const float* tm_b2 = (const float*)d_in[14];
  const float* wm_w1 = (const float*)d_in[15];  const float* wm_b1 = (const float*)d_in[16];
  const float* wm_w2 = (const float*)d_in[17];  const float* wm_b2 = (const float*)d_in[18];
  const float* wq_w  = (const float*)d_in[19];  const float* wq_b  = (const float*)d_in[20];
  const float* wk_w  = (const float*)d_in[21];  const float* wk_b  = (const float*)d_in[22];
  const float* wv1_w = (const float*)d_in[23];  const float* wv1_b = (const float*)d_in[24];
  const float* wv2_w = (const float*)d_in[25];  const float* wv2_b = (const float*)d_in[26];

  float* ws   = (float*)d_ws;
  unsigned short* wsu = (unsigned short*)d_ws;
  float* out  = (float*)d_out;
  float* hbuf = out + DO_H;

  PrepP p;
  const float* tsr[3] = {wk_w, wv1_w, wv2_w};
  int tO[3]  = {64, 64, 16};
  int tK[3]  = {16, 80, 64};
  int tOf[3] = {T_WK, T_WV1, T_WV2};
  for (int i = 0; i < 3; i++) { p.tsrc[i] = tsr[i]; p.tO[i] = tO[i]; p.tK[i] = tK[i]; p.tOff[i] = tOf[i]; }
  const float* ssr[8] = {wm_w1, wm_w2, wq_w, tm_w1, tm_w2, fc1_w, wih, whh};
  int sO[8]  = {256, 128, 64, 256, 16, 64, 192, 192};
  int sK[8]  = {256, 256, 256, 64, 256, 160, 64, 64};
  int sKs[8] = {256, 256, 256, 64, 256, 152, 64, 64};
  int sSt[8] = {256, 256, 256, 72, 256, 152, 64, 64};
  int sOf[8] = {B_WM1*2, B_WM2*2, B_WQ*2, B_TM1*2, B_TM2*2, B_FC1*2, B_WIH*2, B_WHH*2};
  for (int i = 0; i < 8; i++) {
    p.ssrc[i] = ssr[i]; p.sO[i] = sO[i]; p.sK[i] = sK[i];
    p.sKs[i] = sKs[i]; p.sSt[i] = sSt[i]; p.sOff[i] = sOf[i];
  }
  p.tm_w1 = tm_w1; p.tm_b1 = tm_b1;

  k_prep<<<48, 256, 0, stream>>>(p, ws, wsu);
  k_trunk<<<TRUNK_BLOCKS + TRUNK_EXTRA, 512, 0, stream>>>(inputs, hidden,
      wsu + B_FC1*2, wsu + B_WIH*2, wsu + B_WHH*2, fc1_b, bih, bhh, hbuf, p, ws, wsu);
  k_tm<<<ROWS / 32, 512, 0, stream>>>(hbuf, wsu + B_TM1*2, wsu + B_TM2*2,
      ws + TMB, tm_b2, u, ws + O_ACT, ws + O_L1P);
  k_wm<<<ROWS / 32, 512, 0, stream>>>(obs, ws + O_ACT,
      wsu + B_WM1*2, wsu + B_WM2*2, wsu + B_WQ*2, wm_b1, wm_b2, wq_b, obs_next,
      wsu + O_QRY * 2, ws + O_L2P);
  k_kva<<<ROWS / 32, 512, 0, stream>>>(hbuf, ws + O_ACT, ws, wk_b, wv1_b, wv2_b,
      wsu + O_QRY * 2, ws + O_L1P, ws + O_L2P, out);
}